// Round 3
// baseline (1535.636 us; speedup 1.0000x reference)
//
#include <hip/hip_runtime.h>
#include <stdint.h>

typedef unsigned short u16;
typedef __bf16 bf16x8 __attribute__((ext_vector_type(8)));
typedef unsigned short u16x8 __attribute__((ext_vector_type(8)));
typedef float f32x4 __attribute__((ext_vector_type(4)));

#define BSZ 2
#define SEQ 2048
#define DIM 1024
#define D_INNER 2048
#define DT_RANK 64
#define D_STATE 16
#define XPROJ_N 96   // DT_RANK + 2*D_STATE

__device__ __forceinline__ float bf2f(u16 h) {
    return __uint_as_float(((unsigned)h) << 16);
}
__device__ __forceinline__ u16 f2bf(float f) {
    unsigned u = __float_as_uint(f);
    unsigned r = (u + 0x7FFFu + ((u >> 16) & 1u)) >> 16;
    return (u16)r;
}

__device__ __forceinline__ f32x4 mfma16(bf16x8 a, bf16x8 b, f32x4 c) {
    return __builtin_amdgcn_mfma_f32_16x16x32_bf16(a, b, c, 0, 0, 0);
}

// split 8 contiguous f32 into bf16 hi + bf16 lo (residual) fragments
__device__ __forceinline__ void split8(const float* __restrict__ p, bf16x8& hi, bf16x8& lo) {
    f32x4 v0 = *(const f32x4*)p;
    f32x4 v1 = *(const f32x4*)(p + 4);
    u16x8 h, l;
    #pragma unroll
    for (int i = 0; i < 4; i++) {
        float a = v0[i];
        u16 ha = f2bf(a);
        h[i] = ha;
        l[i] = f2bf(a - bf2f(ha));
        float b = v1[i];
        u16 hb = f2bf(b);
        h[4 + i] = hb;
        l[4 + i] = f2bf(b - bf2f(hb));
    }
    hi = __builtin_bit_cast(bf16x8, h);
    lo = __builtin_bit_cast(bf16x8, l);
}

enum { EPI_XZ = 0, EPI_F32 = 1, EPI_SOFTPLUS = 2 };
enum { A_BF16 = 0, A_F32 = 1 };

// C[M,N] = A[M,K(lda)] @ B[N,K(ldb)]^T ; one wave per 32x32 tile.
// B always f32, split hi/lo in-register (2 MFMA terms). A either bf16 (as-is)
// or f32 (split hi/lo, 3 MFMA terms). f32 accumulate.
template<int AMODE, int EPI>
__global__ __launch_bounds__(64)
void gemm_bt(const void* __restrict__ Av, int lda,
             const float* __restrict__ B, int ldb,
             void* __restrict__ C, void* __restrict__ C2, int ldc,
             int K, const float* __restrict__ bias)
{
    const int lane = threadIdx.x;
    const int r16  = lane & 15;
    const int quad = lane >> 4;
    const long m0 = (long)blockIdx.y * 32;
    const long n0 = (long)blockIdx.x * 32;

    const float* Bp0 = B + (n0 + r16) * (long)ldb + quad * 8;
    const float* Bp1 = Bp0 + 16L * ldb;

    f32x4 acc00 = {0.f,0.f,0.f,0.f}, acc01 = {0.f,0.f,0.f,0.f};
    f32x4 acc10 = {0.f,0.f,0.f,0.f}, acc11 = {0.f,0.f,0.f,0.f};

    const float* Af0 = (const float*)Av + (m0 + r16) * (long)lda + quad * 8;
    const float* Af1 = Af0 + 16L * lda;
    const u16*   Ab0 = (const u16*)Av + (m0 + r16) * (long)lda + quad * 8;
    const u16*   Ab1 = Ab0 + 16L * lda;

    for (int k = 0; k < K; k += 32) {
        bf16x8 b0h, b0l, b1h, b1l;
        split8(Bp0 + k, b0h, b0l);
        split8(Bp1 + k, b1h, b1l);
        if (AMODE == A_F32) {
            bf16x8 a0h, a0l, a1h, a1l;
            split8(Af0 + k, a0h, a0l);
            split8(Af1 + k, a1h, a1l);
            acc00 = mfma16(a0h, b0h, acc00); acc00 = mfma16(a0h, b0l, acc00); acc00 = mfma16(a0l, b0h, acc00);
            acc01 = mfma16(a0h, b1h, acc01); acc01 = mfma16(a0h, b1l, acc01); acc01 = mfma16(a0l, b1h, acc01);
            acc10 = mfma16(a1h, b0h, acc10); acc10 = mfma16(a1h, b0l, acc10); acc10 = mfma16(a1l, b0h, acc10);
            acc11 = mfma16(a1h, b1h, acc11); acc11 = mfma16(a1h, b1l, acc11); acc11 = mfma16(a1l, b1h, acc11);
        } else {
            bf16x8 a0 = *(const bf16x8*)(Ab0 + k);
            bf16x8 a1 = *(const bf16x8*)(Ab1 + k);
            acc00 = mfma16(a0, b0h, acc00); acc00 = mfma16(a0, b0l, acc00);
            acc01 = mfma16(a0, b1h, acc01); acc01 = mfma16(a0, b1l, acc01);
            acc10 = mfma16(a1, b0h, acc10); acc10 = mfma16(a1, b0l, acc10);
            acc11 = mfma16(a1, b1h, acc11); acc11 = mfma16(a1, b1l, acc11);
        }
    }

    #pragma unroll
    for (int i = 0; i < 2; i++) {
        #pragma unroll
        for (int j = 0; j < 2; j++) {
            f32x4 v = (i == 0) ? (j == 0 ? acc00 : acc01)
                               : (j == 0 ? acc10 : acc11);
            long col = n0 + j * 16 + r16;
            #pragma unroll
            for (int r = 0; r < 4; r++) {
                long row = m0 + i * 16 + quad * 4 + r;
                float x = v[r];
                if (EPI == EPI_XZ) {
                    // cols [0,2048): xc as bf16 ; cols [2048,4096): z as f32
                    if (col < D_INNER) ((u16*)C)[row * (long)D_INNER + col] = f2bf(x);
                    else ((float*)C2)[row * (long)D_INNER + (col - D_INNER)] = x;
                } else if (EPI == EPI_SOFTPLUS) {
                    x += bias[col];
                    x = (x > 15.f) ? x : log1pf(__expf(x));
                    ((float*)C)[row * (long)ldc + col] = x;
                } else {
                    ((float*)C)[row * (long)ldc + col] = x;
                }
            }
        }
    }
}

// depthwise causal conv(4) + bias + silu : xc (bf16 [4096,2048]) -> u (bf16)
__global__ __launch_bounds__(256)
void conv_silu(const u16* __restrict__ xc, const float* __restrict__ cw,
               const float* __restrict__ cb, u16* __restrict__ u)
{
    int idx = blockIdx.x * 256 + threadIdx.x;   // (b*2048+t)*2048 + d
    int d = idx & 2047;
    int t = (idx >> 11) & 2047;
    float acc = cb[d];
    #pragma unroll
    for (int j = 0; j < 4; j++) {
        int tt = t - 3 + j;
        if (tt >= 0) acc += cw[d * 4 + j] * bf2f(xc[idx + (long)(j - 3) * D_INNER]);
    }
    float s = acc / (1.f + __expf(-acc));
    u[idx] = f2bf(s);
}

#define SCAN_T 64
// one wave per block: 4 channels x 16 states; sequential over t in LDS chunks
__global__ __launch_bounds__(64)
void scan_kernel(const float* __restrict__ delta, const u16* __restrict__ u,
                 const float* __restrict__ xdbc, const float* __restrict__ z,
                 const float* __restrict__ A_log, const float* __restrict__ Dp,
                 u16* __restrict__ y)
{
    const int lane = threadIdx.x;
    const int s    = lane & 15;
    const int dsub = lane >> 4;       // 0..3
    const int b    = blockIdx.y;
    const int d0   = blockIdx.x * 4;
    const int d    = d0 + dsub;

    __shared__ float s_delta[SCAN_T * 4];
    __shared__ float s_u[SCAN_T * 4];
    __shared__ float s_z[SCAN_T * 4];
    __shared__ float s_B[SCAN_T * 16];
    __shared__ float s_C[SCAN_T * 16];

    const float Af = -__expf(A_log[d * 16 + s]) * 1.44269504f;  // A*log2(e)
    const float Dd = Dp[d];
    float h = 0.f;

    for (int t0 = 0; t0 < SEQ; t0 += SCAN_T) {
        __syncthreads();
        for (int i = lane; i < SCAN_T * 4; i += 64) {
            int tt = i >> 2, dd = i & 3;
            long g = (long)(b * SEQ + t0 + tt);
            s_delta[i] = delta[g * D_INNER + d0 + dd];
            s_u[i]     = bf2f(u[g * D_INNER + d0 + dd]);
            s_z[i]     = z[g * D_INNER + d0 + dd];
        }
        for (int i = lane; i < SCAN_T * 16; i += 64) {
            int tt = i >> 4, ss = i & 15;
            long g = (long)(b * SEQ + t0 + tt) * XPROJ_N;
            s_B[i] = xdbc[g + DT_RANK + ss];
            s_C[i] = xdbc[g + DT_RANK + D_STATE + ss];
        }
        __syncthreads();

        for (int t = 0; t < SCAN_T; t++) {
            float dl = s_delta[t * 4 + dsub];
            float uu = s_u[t * 4 + dsub];
            float Bs = s_B[t * 16 + s];
            float Cs = s_C[t * 16 + s];
            float dA = exp2f(dl * Af);
            h = h * dA + dl * uu * Bs;
            float p = h * Cs;
            p += __shfl_xor(p, 1);
            p += __shfl_xor(p, 2);
            p += __shfl_xor(p, 4);
            p += __shfl_xor(p, 8);
            if (s == 0) {
                float zl = s_z[t * 4 + dsub];
                float sz = zl / (1.f + __expf(-zl));
                float yy = (p + uu * Dd) * sz;
                y[(long)(b * SEQ + t0 + t) * D_INNER + d] = f2bf(yy);
            }
        }
    }
}

__global__ __launch_bounds__(256)
void layernorm_kernel(const float* __restrict__ pre, const float* __restrict__ gamma,
                      const float* __restrict__ beta, float* __restrict__ out)
{
    const long row = blockIdx.x;
    const float* p = pre + row * DIM;
    int tid = threadIdx.x;
    float v[4];
    float sum = 0.f, sq = 0.f;
    #pragma unroll
    for (int i = 0; i < 4; i++) {
        v[i] = p[tid + i * 256];
        sum += v[i];
        sq  += v[i] * v[i];
    }
    #pragma unroll
    for (int off = 1; off < 64; off <<= 1) {
        sum += __shfl_xor(sum, off);
        sq  += __shfl_xor(sq, off);
    }
    __shared__ float ssum[4], ssq[4];
    int w = tid >> 6;
    if ((tid & 63) == 0) { ssum[w] = sum; ssq[w] = sq; }
    __syncthreads();
    float ts = ssum[0] + ssum[1] + ssum[2] + ssum[3];
    float tq = ssq[0] + ssq[1] + ssq[2] + ssq[3];
    float mean = ts * (1.f / DIM);
    float var  = tq * (1.f / DIM) - mean * mean;
    float rstd = rsqrtf(var + 1e-5f);
    float* o = out + row * DIM;
    #pragma unroll
    for (int i = 0; i < 4; i++) {
        int c = tid + i * 256;
        o[c] = (v[i] - mean) * rstd * gamma[c] + beta[c];
    }
}

extern "C" void kernel_launch(void* const* d_in, const int* in_sizes, int n_in,
                              void* d_out, int out_size, void* d_ws, size_t ws_size,
                              hipStream_t stream)
{
    const float* x      = (const float*)d_in[0];
    const float* W_in   = (const float*)d_in[1];
    const float* conv_w = (const float*)d_in[2];
    const float* conv_b = (const float*)d_in[3];
    const float* W_xproj= (const float*)d_in[4];
    const float* W_dt   = (const float*)d_in[5];
    const float* b_dt   = (const float*)d_in[6];
    const float* A_log  = (const float*)d_in[7];
    const float* Dv     = (const float*)d_in[8];
    const float* W_out  = (const float*)d_in[9];
    const float* gamma  = (const float*)d_in[10];
    const float* beta   = (const float*)d_in[11];

    char* ws = (char*)d_ws;
    u16*   xc    = (u16*)(ws);                   // [0,   16M)  4096x2048 bf16
    float* z     = (float*)(ws + 16777216);      // [16M, 48M)  4096x2048 f32
    u16*   u     = (u16*)(ws + 50331648);        // [48M, 64M)  4096x2048 bf16
    float* xdbc  = (float*)(ws + 67108864);      // [64M, 65.5M) 4096x96 f32
    float* delta = (float*)(ws + 68681728);      // [65.5M, 97.5M) 4096x2048 f32
    u16*   yb    = (u16*)(ws);                   // alias xc (dead after conv)
    float* opre  = (float*)(ws + 16777216);      // alias z (dead after scan)

    // 1) xz = x @ W_in^T  (M=4096, N=4096, K=1024) -> xc bf16 | z f32
    gemm_bt<A_F32, EPI_XZ><<<dim3(128, 128), 64, 0, stream>>>(
        x, DIM, W_in, DIM, xc, z, 0, DIM, nullptr);
    // 2) u = silu(causal_conv4(xc) + cb)
    conv_silu<<<32768, 256, 0, stream>>>(xc, conv_w, conv_b, u);
    // 3) xdbc = u @ W_xproj^T  (M=4096, N=96, K=2048) -> f32
    gemm_bt<A_BF16, EPI_F32><<<dim3(3, 128), 64, 0, stream>>>(
        u, D_INNER, W_xproj, D_INNER, xdbc, nullptr, XPROJ_N, D_INNER, nullptr);
    // 4) delta = softplus(dt @ W_dt^T + b_dt)  (M=4096, N=2048, K=64) -> f32
    gemm_bt<A_F32, EPI_SOFTPLUS><<<dim3(64, 128), 64, 0, stream>>>(
        xdbc, XPROJ_N, W_dt, DT_RANK, delta, nullptr, D_INNER, DT_RANK, b_dt);
    // 5) selective scan + (+u*D) * silu(z) -> yb bf16
    scan_kernel<<<dim3(512, 2), 64, 0, stream>>>(delta, u, xdbc, z, A_log, Dv, yb);
    // 6) opre = yb @ W_out^T  (M=4096, N=1024, K=2048) -> f32
    gemm_bt<A_BF16, EPI_F32><<<dim3(32, 128), 64, 0, stream>>>(
        yb, D_INNER, W_out, D_INNER, opre, nullptr, DIM, D_INNER, nullptr);
    // 7) layernorm -> d_out f32
    layernorm_kernel<<<4096, 256, 0, stream>>>(opre, gamma, beta, (float*)d_out);
}

// Round 4
// 1020.774 us; speedup vs baseline: 1.5044x; 1.5044x over previous
//
#include <hip/hip_runtime.h>
#include <stdint.h>

typedef unsigned short u16;
typedef __bf16 bf16x8 __attribute__((ext_vector_type(8)));
typedef unsigned short u16x8 __attribute__((ext_vector_type(8)));
typedef float f32x4 __attribute__((ext_vector_type(4)));

#define BSZ 2
#define SEQ 2048
#define DIM 1024
#define D_INNER 2048
#define DT_RANK 64
#define D_STATE 16
#define XPROJ_N 96   // DT_RANK + 2*D_STATE
#define NCHUNK 32
#define CHUNK_T 64   // SEQ / NCHUNK
#define LOG2E 1.44269504f

__device__ __forceinline__ float bf2f(u16 h) {
    return __uint_as_float(((unsigned)h) << 16);
}
__device__ __forceinline__ u16 f2bf(float f) {
    unsigned u = __float_as_uint(f);
    unsigned r = (u + 0x7FFFu + ((u >> 16) & 1u)) >> 16;
    return (u16)r;
}

__device__ __forceinline__ f32x4 mfma16(bf16x8 a, bf16x8 b, f32x4 c) {
    return __builtin_amdgcn_mfma_f32_16x16x32_bf16(a, b, c, 0, 0, 0);
}

// split 8 contiguous f32 into bf16 hi + bf16 lo (residual) fragments
__device__ __forceinline__ void split8(const float* __restrict__ p, bf16x8& hi, bf16x8& lo) {
    f32x4 v0 = *(const f32x4*)p;
    f32x4 v1 = *(const f32x4*)(p + 4);
    u16x8 h, l;
    #pragma unroll
    for (int i = 0; i < 4; i++) {
        float a = v0[i];
        u16 ha = f2bf(a);
        h[i] = ha;
        l[i] = f2bf(a - bf2f(ha));
        float b = v1[i];
        u16 hb = f2bf(b);
        h[4 + i] = hb;
        l[4 + i] = f2bf(b - bf2f(hb));
    }
    hi = __builtin_bit_cast(bf16x8, h);
    lo = __builtin_bit_cast(bf16x8, l);
}

enum { EPI_XZ = 0, EPI_F32 = 1, EPI_SOFTPLUS = 2 };
enum { A_BF16 = 0, A_F32 = 1 };

// C[M,N] = A[M,K(lda)] @ B[N,K(ldb)]^T ; one wave per 32x32 tile.
// B always f32, split hi/lo in-register (2 MFMA terms). A either bf16 (as-is)
// or f32 (split hi/lo, 3 MFMA terms). f32 accumulate.
template<int AMODE, int EPI>
__global__ __launch_bounds__(64)
void gemm_bt(const void* __restrict__ Av, int lda,
             const float* __restrict__ B, int ldb,
             void* __restrict__ C, void* __restrict__ C2, int ldc,
             int K, const float* __restrict__ bias)
{
    const int lane = threadIdx.x;
    const int r16  = lane & 15;
    const int quad = lane >> 4;
    const long m0 = (long)blockIdx.y * 32;
    const long n0 = (long)blockIdx.x * 32;

    const float* Bp0 = B + (n0 + r16) * (long)ldb + quad * 8;
    const float* Bp1 = Bp0 + 16L * ldb;

    f32x4 acc00 = {0.f,0.f,0.f,0.f}, acc01 = {0.f,0.f,0.f,0.f};
    f32x4 acc10 = {0.f,0.f,0.f,0.f}, acc11 = {0.f,0.f,0.f,0.f};

    const float* Af0 = (const float*)Av + (m0 + r16) * (long)lda + quad * 8;
    const float* Af1 = Af0 + 16L * lda;
    const u16*   Ab0 = (const u16*)Av + (m0 + r16) * (long)lda + quad * 8;
    const u16*   Ab1 = Ab0 + 16L * lda;

    for (int k = 0; k < K; k += 32) {
        bf16x8 b0h, b0l, b1h, b1l;
        split8(Bp0 + k, b0h, b0l);
        split8(Bp1 + k, b1h, b1l);
        if (AMODE == A_F32) {
            bf16x8 a0h, a0l, a1h, a1l;
            split8(Af0 + k, a0h, a0l);
            split8(Af1 + k, a1h, a1l);
            acc00 = mfma16(a0h, b0h, acc00); acc00 = mfma16(a0h, b0l, acc00); acc00 = mfma16(a0l, b0h, acc00);
            acc01 = mfma16(a0h, b1h, acc01); acc01 = mfma16(a0h, b1l, acc01); acc01 = mfma16(a0l, b1h, acc01);
            acc10 = mfma16(a1h, b0h, acc10); acc10 = mfma16(a1h, b0l, acc10); acc10 = mfma16(a1l, b0h, acc10);
            acc11 = mfma16(a1h, b1h, acc11); acc11 = mfma16(a1h, b1l, acc11); acc11 = mfma16(a1l, b1h, acc11);
        } else {
            bf16x8 a0 = *(const bf16x8*)(Ab0 + k);
            bf16x8 a1 = *(const bf16x8*)(Ab1 + k);
            acc00 = mfma16(a0, b0h, acc00); acc00 = mfma16(a0, b0l, acc00);
            acc01 = mfma16(a0, b1h, acc01); acc01 = mfma16(a0, b1l, acc01);
            acc10 = mfma16(a1, b0h, acc10); acc10 = mfma16(a1, b0l, acc10);
            acc11 = mfma16(a1, b1h, acc11); acc11 = mfma16(a1, b1l, acc11);
        }
    }

    #pragma unroll
    for (int i = 0; i < 2; i++) {
        #pragma unroll
        for (int j = 0; j < 2; j++) {
            f32x4 v = (i == 0) ? (j == 0 ? acc00 : acc01)
                               : (j == 0 ? acc10 : acc11);
            long col = n0 + j * 16 + r16;
            #pragma unroll
            for (int r = 0; r < 4; r++) {
                long row = m0 + i * 16 + quad * 4 + r;
                float x = v[r];
                if (EPI == EPI_XZ) {
                    // cols [0,2048): xc as bf16 ; cols [2048,4096): z as f32
                    if (col < D_INNER) ((u16*)C)[row * (long)D_INNER + col] = f2bf(x);
                    else ((float*)C2)[row * (long)D_INNER + (col - D_INNER)] = x;
                } else if (EPI == EPI_SOFTPLUS) {
                    x += bias[col];
                    x = (x > 15.f) ? x : log1pf(__expf(x));
                    ((float*)C)[row * (long)ldc + col] = x;
                } else {
                    ((float*)C)[row * (long)ldc + col] = x;
                }
            }
        }
    }
}

// depthwise causal conv(4) + bias + silu : xc (bf16 [4096,2048]) -> u (bf16)
__global__ __launch_bounds__(256)
void conv_silu(const u16* __restrict__ xc, const float* __restrict__ cw,
               const float* __restrict__ cb, u16* __restrict__ u)
{
    int idx = blockIdx.x * 256 + threadIdx.x;   // (b*2048+t)*2048 + d
    int d = idx & 2047;
    int t = (idx >> 11) & 2047;
    float acc = cb[d];
    #pragma unroll
    for (int j = 0; j < 4; j++) {
        int tt = t - 3 + j;
        if (tt >= 0) acc += cw[d * 4 + j] * bf2f(xc[idx + (long)(j - 3) * D_INNER]);
    }
    float s = acc / (1.f + __expf(-acc));
    u[idx] = f2bf(s);
}

// ---- chunked parallel scan: pass A ----
// grid (8, NCHUNK, BSZ) x 256 threads; lane owns channel d = bx*256+tid,
// computes local scan (h0=0) over its 64-step chunk; stores h_end + sum(delta).
__global__ __launch_bounds__(256)
void scan_partA(const float* __restrict__ delta, const u16* __restrict__ u,
                const float* __restrict__ xdbc, const float* __restrict__ A_log,
                float* __restrict__ hbuf, float* __restrict__ sdelta)
{
    const int d = blockIdx.x * 256 + threadIdx.x;
    const int c = blockIdx.y;
    const int b = blockIdx.z;
    const int t0 = c * CHUNK_T;

    float Af[16];
    #pragma unroll
    for (int s = 0; s < 16; s++) Af[s] = -__expf(A_log[d * 16 + s]) * LOG2E;

    float h[16];
    #pragma unroll
    for (int s = 0; s < 16; s++) h[s] = 0.f;
    float sd = 0.f;

    const float* dptr = delta + ((long)b * SEQ + t0) * D_INNER + d;
    const u16*   uptr = u     + ((long)b * SEQ + t0) * D_INNER + d;
    const float* xp   = xdbc  + ((long)b * SEQ + t0) * XPROJ_N;

    for (int t = 0; t < CHUNK_T; t++) {
        float dl = dptr[(long)t * D_INNER];
        float uu = bf2f(uptr[(long)t * D_INNER]);
        f32x4 B0 = *(const f32x4*)(xp + t * XPROJ_N + DT_RANK);
        f32x4 B1 = *(const f32x4*)(xp + t * XPROJ_N + DT_RANK + 4);
        f32x4 B2 = *(const f32x4*)(xp + t * XPROJ_N + DT_RANK + 8);
        f32x4 B3 = *(const f32x4*)(xp + t * XPROJ_N + DT_RANK + 12);
        float Bv[16] = {B0[0],B0[1],B0[2],B0[3], B1[0],B1[1],B1[2],B1[3],
                        B2[0],B2[1],B2[2],B2[3], B3[0],B3[1],B3[2],B3[3]};
        sd += dl;
        float dlu = dl * uu;
        #pragma unroll
        for (int s = 0; s < 16; s++)
            h[s] = h[s] * exp2f(dl * Af[s]) + dlu * Bv[s];
    }

    float* hout = hbuf + ((long)(b * NCHUNK + c) * D_INNER + d) * 16;
    #pragma unroll
    for (int s = 0; s < 16; s++) hout[s] = h[s];
    sdelta[(long)(b * NCHUNK + c) * D_INNER + d] = sd;
}

// ---- pass B: compose chunk boundaries (in-place: hbuf h_end -> h_in) ----
__global__ __launch_bounds__(256)
void scan_fixup(float* __restrict__ hbuf, const float* __restrict__ sdelta,
                const float* __restrict__ A_log)
{
    const int idx = blockIdx.x * 256 + threadIdx.x;   // 65536 threads
    const int ds = idx & (D_INNER * 16 - 1);
    const int b  = idx >> 15;
    const float Af = -__expf(A_log[ds]) * LOG2E;
    float hin = 0.f;
    #pragma unroll 4
    for (int c = 0; c < NCHUNK; c++) {
        long gi = (long)(b * NCHUNK + c) * (D_INNER * 16) + ds;
        float e = hbuf[gi];
        hbuf[gi] = hin;   // overwrite h_end with h_in
        float sd = sdelta[(long)(b * NCHUNK + c) * D_INNER + (ds >> 4)];
        hin = e + exp2f(Af * sd) * hin;
    }
}

// ---- pass C: full scan from h_in, fused +u*D and *silu(z), write y (bf16) ----
__global__ __launch_bounds__(256)
void scan_partC(const float* __restrict__ delta, const u16* __restrict__ u,
                const float* __restrict__ xdbc, const float* __restrict__ z,
                const float* __restrict__ A_log, const float* __restrict__ Dp,
                const float* __restrict__ hbuf, u16* __restrict__ y)
{
    const int d = blockIdx.x * 256 + threadIdx.x;
    const int c = blockIdx.y;
    const int b = blockIdx.z;
    const int t0 = c * CHUNK_T;

    float Af[16];
    #pragma unroll
    for (int s = 0; s < 16; s++) Af[s] = -__expf(A_log[d * 16 + s]) * LOG2E;
    const float Dd = Dp[d];

    float h[16];
    const float* hin = hbuf + ((long)(b * NCHUNK + c) * D_INNER + d) * 16;
    #pragma unroll
    for (int s = 0; s < 16; s++) h[s] = hin[s];

    const float* dptr = delta + ((long)b * SEQ + t0) * D_INNER + d;
    const u16*   uptr = u     + ((long)b * SEQ + t0) * D_INNER + d;
    const float* zptr = z     + ((long)b * SEQ + t0) * D_INNER + d;
    const float* xp   = xdbc  + ((long)b * SEQ + t0) * XPROJ_N;
    u16* yptr = y + ((long)b * SEQ + t0) * D_INNER + d;

    for (int t = 0; t < CHUNK_T; t++) {
        float dl = dptr[(long)t * D_INNER];
        float uu = bf2f(uptr[(long)t * D_INNER]);
        float zl = zptr[(long)t * D_INNER];
        f32x4 B0 = *(const f32x4*)(xp + t * XPROJ_N + DT_RANK);
        f32x4 B1 = *(const f32x4*)(xp + t * XPROJ_N + DT_RANK + 4);
        f32x4 B2 = *(const f32x4*)(xp + t * XPROJ_N + DT_RANK + 8);
        f32x4 B3 = *(const f32x4*)(xp + t * XPROJ_N + DT_RANK + 12);
        f32x4 C0 = *(const f32x4*)(xp + t * XPROJ_N + DT_RANK + 16);
        f32x4 C1 = *(const f32x4*)(xp + t * XPROJ_N + DT_RANK + 20);
        f32x4 C2 = *(const f32x4*)(xp + t * XPROJ_N + DT_RANK + 24);
        f32x4 C3 = *(const f32x4*)(xp + t * XPROJ_N + DT_RANK + 28);
        float Bv[16] = {B0[0],B0[1],B0[2],B0[3], B1[0],B1[1],B1[2],B1[3],
                        B2[0],B2[1],B2[2],B2[3], B3[0],B3[1],B3[2],B3[3]};
        float Cv[16] = {C0[0],C0[1],C0[2],C0[3], C1[0],C1[1],C1[2],C1[3],
                        C2[0],C2[1],C2[2],C2[3], C3[0],C3[1],C3[2],C3[3]};
        float dlu = dl * uu;
        float p0 = 0.f, p1 = 0.f, p2 = 0.f, p3 = 0.f;
        #pragma unroll
        for (int s = 0; s < 16; s += 4) {
            h[s]   = h[s]   * exp2f(dl * Af[s])   + dlu * Bv[s];
            h[s+1] = h[s+1] * exp2f(dl * Af[s+1]) + dlu * Bv[s+1];
            h[s+2] = h[s+2] * exp2f(dl * Af[s+2]) + dlu * Bv[s+2];
            h[s+3] = h[s+3] * exp2f(dl * Af[s+3]) + dlu * Bv[s+3];
            p0 += h[s]   * Cv[s];
            p1 += h[s+1] * Cv[s+1];
            p2 += h[s+2] * Cv[s+2];
            p3 += h[s+3] * Cv[s+3];
        }
        float acc = (p0 + p1) + (p2 + p3);
        float sz = zl / (1.f + __expf(-zl));
        float yy = (acc + uu * Dd) * sz;
        yptr[(long)t * D_INNER] = f2bf(yy);
    }
}

__global__ __launch_bounds__(256)
void layernorm_kernel(const float* __restrict__ pre, const float* __restrict__ gamma,
                      const float* __restrict__ beta, float* __restrict__ out)
{
    const long row = blockIdx.x;
    const float* p = pre + row * DIM;
    int tid = threadIdx.x;
    float v[4];
    float sum = 0.f, sq = 0.f;
    #pragma unroll
    for (int i = 0; i < 4; i++) {
        v[i] = p[tid + i * 256];
        sum += v[i];
        sq  += v[i] * v[i];
    }
    #pragma unroll
    for (int off = 1; off < 64; off <<= 1) {
        sum += __shfl_xor(sum, off);
        sq  += __shfl_xor(sq, off);
    }
    __shared__ float ssum[4], ssq[4];
    int w = tid >> 6;
    if ((tid & 63) == 0) { ssum[w] = sum; ssq[w] = sq; }
    __syncthreads();
    float ts = ssum[0] + ssum[1] + ssum[2] + ssum[3];
    float tq = ssq[0] + ssq[1] + ssq[2] + ssq[3];
    float mean = ts * (1.f / DIM);
    float var  = tq * (1.f / DIM) - mean * mean;
    float rstd = rsqrtf(var + 1e-5f);
    float* o = out + row * DIM;
    #pragma unroll
    for (int i = 0; i < 4; i++) {
        int c = tid + i * 256;
        o[c] = (v[i] - mean) * rstd * gamma[c] + beta[c];
    }
}

extern "C" void kernel_launch(void* const* d_in, const int* in_sizes, int n_in,
                              void* d_out, int out_size, void* d_ws, size_t ws_size,
                              hipStream_t stream)
{
    const float* x      = (const float*)d_in[0];
    const float* W_in   = (const float*)d_in[1];
    const float* conv_w = (const float*)d_in[2];
    const float* conv_b = (const float*)d_in[3];
    const float* W_xproj= (const float*)d_in[4];
    const float* W_dt   = (const float*)d_in[5];
    const float* b_dt   = (const float*)d_in[6];
    const float* A_log  = (const float*)d_in[7];
    const float* Dv     = (const float*)d_in[8];
    const float* W_out  = (const float*)d_in[9];
    const float* gamma  = (const float*)d_in[10];
    const float* beta   = (const float*)d_in[11];

    char* ws = (char*)d_ws;
    u16*   xc    = (u16*)(ws);                   // [0,   16M)  4096x2048 bf16 (dead after conv)
    float* z     = (float*)(ws + 16777216);      // [16M, 48M)  4096x2048 f32  (dead after scanC)
    u16*   u     = (u16*)(ws + 50331648);        // [48M, 64M)  4096x2048 bf16
    float* xdbc  = (float*)(ws + 67108864);      // [64M, 65.5M) 4096x96 f32
    float* delta = (float*)(ws + 68681728);      // [65.5M, 97.5M) 4096x2048 f32
    float* hbuf  = (float*)(ws);                 // alias xc: 2*32*2048*16 f32 = 8 MB
    float* sdel  = (float*)(ws + 8388608);       // alias xc+8M: 0.5 MB
    u16*   yb    = (u16*)d_out;                  // stage y in d_out (16 MB, == out bytes)
    float* opre  = (float*)(ws + 16777216);      // alias z (dead after scanC)

    // 1) xz = x @ W_in^T  (M=4096, N=4096, K=1024) -> xc bf16 | z f32
    gemm_bt<A_F32, EPI_XZ><<<dim3(128, 128), 64, 0, stream>>>(
        x, DIM, W_in, DIM, xc, z, 0, DIM, nullptr);
    // 2) u = silu(causal_conv4(xc) + cb)
    conv_silu<<<32768, 256, 0, stream>>>(xc, conv_w, conv_b, u);
    // 3) xdbc = u @ W_xproj^T  (M=4096, N=96, K=2048) -> f32
    gemm_bt<A_BF16, EPI_F32><<<dim3(3, 128), 64, 0, stream>>>(
        u, D_INNER, W_xproj, D_INNER, xdbc, nullptr, XPROJ_N, D_INNER, nullptr);
    // 4) delta = softplus(dt @ W_dt^T + b_dt)  (M=4096, N=2048, K=64) -> f32
    gemm_bt<A_F32, EPI_SOFTPLUS><<<dim3(64, 128), 64, 0, stream>>>(
        xdbc, XPROJ_N, W_dt, DT_RANK, delta, nullptr, D_INNER, DT_RANK, b_dt);
    // 5) chunked parallel scan: A (local scans) -> B (boundary compose) -> C (final + gate)
    scan_partA<<<dim3(8, NCHUNK, BSZ), 256, 0, stream>>>(delta, u, xdbc, A_log, hbuf, sdel);
    scan_fixup<<<256, 256, 0, stream>>>(hbuf, sdel, A_log);
    scan_partC<<<dim3(8, NCHUNK, BSZ), 256, 0, stream>>>(delta, u, xdbc, z, A_log, Dv, hbuf, yb);
    // 6) opre = yb @ W_out^T  (M=4096, N=1024, K=2048) -> f32
    gemm_bt<A_BF16, EPI_F32><<<dim3(32, 128), 64, 0, stream>>>(
        yb, D_INNER, W_out, D_INNER, opre, nullptr, DIM, D_INNER, nullptr);
    // 7) layernorm -> d_out f32 (overwrites yb staging after gemm4 consumed it)
    layernorm_kernel<<<4096, 256, 0, stream>>>(opre, gamma, beta, (float*)d_out);
}

// Round 5
// 685.992 us; speedup vs baseline: 2.2386x; 1.4880x over previous
//
#include <hip/hip_runtime.h>
#include <stdint.h>

typedef unsigned short u16;
typedef __bf16 bf16x8 __attribute__((ext_vector_type(8)));
typedef float f32x4 __attribute__((ext_vector_type(4)));

#define BSZ 2
#define SEQ 2048
#define DIM 1024
#define D_INNER 2048
#define DT_RANK 64
#define D_STATE 16
#define XPROJ_N 96   // DT_RANK + 2*D_STATE
#define NCHUNK 32
#define CHUNK_T 64   // SEQ / NCHUNK
#define LOG2E 1.44269504f

__device__ __forceinline__ float bf2f(u16 h) {
    return __uint_as_float(((unsigned)h) << 16);
}
__device__ __forceinline__ u16 f2bf(float f) {
    unsigned u = __float_as_uint(f);
    unsigned r = (u + 0x7FFFu + ((u >> 16) & 1u)) >> 16;
    return (u16)r;
}

__device__ __forceinline__ f32x4 mfma16(bf16x8 a, bf16x8 b, f32x4 c) {
    return __builtin_amdgcn_mfma_f32_16x16x32_bf16(a, b, c, 0, 0, 0);
}

// f32 -> bf16 hi + bf16 lo (residual), one pass over the array
__global__ __launch_bounds__(256)
void split_kernel(const float* __restrict__ in, u16* __restrict__ hi,
                  u16* __restrict__ lo, int n)
{
    int i = blockIdx.x * 256 + threadIdx.x;
    if (i < n) {
        float v = in[i];
        u16 h = f2bf(v);
        hi[i] = h;
        lo[i] = f2bf(v - bf2f(h));
    }
}

__global__ __launch_bounds__(256)
void zero_kernel(float* __restrict__ p, int n)
{
    int i = blockIdx.x * 256 + threadIdx.x;
    if (i < n) p[i] = 0.f;
}

enum { EPI_XZ = 0, EPI_F32 = 1, EPI_SOFTPLUS = 2 };

// C[M,N] = A[M,K] @ B[N,K]^T, one wave per 64x64 tile, pre-split bf16 hi/lo.
// TERMS=3: ah*bh + ah*bl + al*bh (A has lo). TERMS=2: A bf16 only, a*bh + a*bl.
template<int TERMS, int EPI>
__global__ __launch_bounds__(64)
void gemm64(const u16* __restrict__ Ah, const u16* __restrict__ Al, int lda,
            const u16* __restrict__ Bh, const u16* __restrict__ Bl, int ldb,
            void* __restrict__ C, void* __restrict__ C2, int ldc,
            int K, const float* __restrict__ bias)
{
    const int lane = threadIdx.x;
    const int r16  = lane & 15;
    const int quad = lane >> 4;
    const long m0 = (long)blockIdx.y * 64;
    const long n0 = (long)blockIdx.x * 64;

    const u16* Ahp[4]; const u16* Alp[4];
    const u16* Bhp[4]; const u16* Blp[4];
    #pragma unroll
    for (int i = 0; i < 4; i++) {
        long ra = (m0 + r16 + 16 * i) * (long)lda + quad * 8;
        long rb = (n0 + r16 + 16 * i) * (long)ldb + quad * 8;
        Ahp[i] = Ah + ra; Alp[i] = (TERMS == 3) ? (Al + ra) : nullptr;
        Bhp[i] = Bh + rb; Blp[i] = Bl + rb;
    }

    f32x4 acc[4][4];
    #pragma unroll
    for (int i = 0; i < 4; i++)
        #pragma unroll
        for (int j = 0; j < 4; j++) acc[i][j] = {0.f, 0.f, 0.f, 0.f};

    for (int k = 0; k < K; k += 32) {
        bf16x8 ah[4], al[4], bh[4], bl[4];
        #pragma unroll
        for (int i = 0; i < 4; i++) {
            ah[i] = *(const bf16x8*)(Ahp[i] + k);
            if (TERMS == 3) al[i] = *(const bf16x8*)(Alp[i] + k);
            bh[i] = *(const bf16x8*)(Bhp[i] + k);
            bl[i] = *(const bf16x8*)(Blp[i] + k);
        }
        #pragma unroll
        for (int i = 0; i < 4; i++) {
            #pragma unroll
            for (int j = 0; j < 4; j++) {
                acc[i][j] = mfma16(ah[i], bh[j], acc[i][j]);
                acc[i][j] = mfma16(ah[i], bl[j], acc[i][j]);
                if (TERMS == 3) acc[i][j] = mfma16(al[i], bh[j], acc[i][j]);
            }
        }
    }

    #pragma unroll
    for (int i = 0; i < 4; i++) {
        #pragma unroll
        for (int j = 0; j < 4; j++) {
            long col = n0 + j * 16 + r16;
            #pragma unroll
            for (int r = 0; r < 4; r++) {
                long row = m0 + i * 16 + quad * 4 + r;
                float x = acc[i][j][r];
                if (EPI == EPI_XZ) {
                    if (col < D_INNER) ((u16*)C)[row * (long)D_INNER + col] = f2bf(x);
                    else ((float*)C2)[row * (long)D_INNER + (col - D_INNER)] = x;
                } else if (EPI == EPI_SOFTPLUS) {
                    x += bias[col];
                    x = (x > 15.f) ? x : log1pf(__expf(x));
                    ((float*)C)[row * (long)ldc + col] = x;
                } else {
                    ((float*)C)[row * (long)ldc + col] = x;
                }
            }
        }
    }
}

// GEMM3: xdbc += u @ W_xproj^T, split-K over blockIdx.z, 32x32 tile per wave
__global__ __launch_bounds__(64)
void gemm3_splitk(const u16* __restrict__ A, int lda,
                  const u16* __restrict__ Bh, const u16* __restrict__ Bl, int ldb,
                  float* __restrict__ C, int ldc, int K0)
{
    const int lane = threadIdx.x;
    const int r16  = lane & 15;
    const int quad = lane >> 4;
    const long m0 = (long)blockIdx.y * 32;
    const long n0 = (long)blockIdx.x * 32;
    const int kbase = blockIdx.z * K0;

    const u16* Ap0 = A  + (m0 + r16) * (long)lda + quad * 8 + kbase;
    const u16* Ap1 = Ap0 + 16L * lda;
    const u16* Bh0 = Bh + (n0 + r16) * (long)ldb + quad * 8 + kbase;
    const u16* Bh1 = Bh0 + 16L * ldb;
    const u16* Bl0 = Bl + (n0 + r16) * (long)ldb + quad * 8 + kbase;
    const u16* Bl1 = Bl0 + 16L * ldb;

    f32x4 acc00 = {0,0,0,0}, acc01 = {0,0,0,0}, acc10 = {0,0,0,0}, acc11 = {0,0,0,0};

    for (int k = 0; k < K0; k += 32) {
        bf16x8 a0 = *(const bf16x8*)(Ap0 + k);
        bf16x8 a1 = *(const bf16x8*)(Ap1 + k);
        bf16x8 b0h = *(const bf16x8*)(Bh0 + k);
        bf16x8 b1h = *(const bf16x8*)(Bh1 + k);
        bf16x8 b0l = *(const bf16x8*)(Bl0 + k);
        bf16x8 b1l = *(const bf16x8*)(Bl1 + k);
        acc00 = mfma16(a0, b0h, acc00); acc00 = mfma16(a0, b0l, acc00);
        acc01 = mfma16(a0, b1h, acc01); acc01 = mfma16(a0, b1l, acc01);
        acc10 = mfma16(a1, b0h, acc10); acc10 = mfma16(a1, b0l, acc10);
        acc11 = mfma16(a1, b1h, acc11); acc11 = mfma16(a1, b1l, acc11);
    }

    #pragma unroll
    for (int i = 0; i < 2; i++) {
        #pragma unroll
        for (int j = 0; j < 2; j++) {
            f32x4 v = (i == 0) ? (j == 0 ? acc00 : acc01) : (j == 0 ? acc10 : acc11);
            long col = n0 + j * 16 + r16;
            #pragma unroll
            for (int r = 0; r < 4; r++) {
                long row = m0 + i * 16 + quad * 4 + r;
                atomicAdd(&C[row * (long)ldc + col], v[r]);
            }
        }
    }
}

// depthwise causal conv(4) + bias + silu : xc (bf16 [4096,2048]) -> u (bf16)
__global__ __launch_bounds__(256)
void conv_silu(const u16* __restrict__ xc, const float* __restrict__ cw,
               const float* __restrict__ cb, u16* __restrict__ u)
{
    int idx = blockIdx.x * 256 + threadIdx.x;   // (b*2048+t)*2048 + d
    int d = idx & 2047;
    int t = (idx >> 11) & 2047;
    float acc = cb[d];
    #pragma unroll
    for (int j = 0; j < 4; j++) {
        int tt = t - 3 + j;
        if (tt >= 0) acc += cw[d * 4 + j] * bf2f(xc[idx + (long)(j - 3) * D_INNER]);
    }
    float s = acc / (1.f + __expf(-acc));
    u[idx] = f2bf(s);
}

// ---- chunked parallel scan: pass A ----
__global__ __launch_bounds__(256)
void scan_partA(const float* __restrict__ delta, const u16* __restrict__ u,
                const float* __restrict__ xdbc, const float* __restrict__ A_log,
                float* __restrict__ hbuf, float* __restrict__ sdelta)
{
    const int d = blockIdx.x * 256 + threadIdx.x;
    const int c = blockIdx.y;
    const int b = blockIdx.z;
    const int t0 = c * CHUNK_T;

    float Af[16];
    #pragma unroll
    for (int s = 0; s < 16; s++) Af[s] = -__expf(A_log[d * 16 + s]) * LOG2E;

    float h[16];
    #pragma unroll
    for (int s = 0; s < 16; s++) h[s] = 0.f;
    float sd = 0.f;

    const float* dptr = delta + ((long)b * SEQ + t0) * D_INNER + d;
    const u16*   uptr = u     + ((long)b * SEQ + t0) * D_INNER + d;
    const float* xp   = xdbc  + ((long)b * SEQ + t0) * XPROJ_N;

    for (int t = 0; t < CHUNK_T; t++) {
        float dl = dptr[(long)t * D_INNER];
        float uu = bf2f(uptr[(long)t * D_INNER]);
        f32x4 B0 = *(const f32x4*)(xp + t * XPROJ_N + DT_RANK);
        f32x4 B1 = *(const f32x4*)(xp + t * XPROJ_N + DT_RANK + 4);
        f32x4 B2 = *(const f32x4*)(xp + t * XPROJ_N + DT_RANK + 8);
        f32x4 B3 = *(const f32x4*)(xp + t * XPROJ_N + DT_RANK + 12);
        float Bv[16] = {B0[0],B0[1],B0[2],B0[3], B1[0],B1[1],B1[2],B1[3],
                        B2[0],B2[1],B2[2],B2[3], B3[0],B3[1],B3[2],B3[3]};
        sd += dl;
        float dlu = dl * uu;
        #pragma unroll
        for (int s = 0; s < 16; s++)
            h[s] = h[s] * exp2f(dl * Af[s]) + dlu * Bv[s];
    }

    float* hout = hbuf + ((long)(b * NCHUNK + c) * D_INNER + d) * 16;
    #pragma unroll
    for (int s = 0; s < 16; s++) hout[s] = h[s];
    sdelta[(long)(b * NCHUNK + c) * D_INNER + d] = sd;
}

// ---- pass B: compose chunk boundaries (in-place: hbuf h_end -> h_in) ----
__global__ __launch_bounds__(256)
void scan_fixup(float* __restrict__ hbuf, const float* __restrict__ sdelta,
                const float* __restrict__ A_log)
{
    const int idx = blockIdx.x * 256 + threadIdx.x;   // 65536 threads
    const int ds = idx & (D_INNER * 16 - 1);
    const int b  = idx >> 15;
    const float Af = -__expf(A_log[ds]) * LOG2E;
    float hin = 0.f;
    #pragma unroll 4
    for (int c = 0; c < NCHUNK; c++) {
        long gi = (long)(b * NCHUNK + c) * (D_INNER * 16) + ds;
        float e = hbuf[gi];
        hbuf[gi] = hin;
        float sd = sdelta[(long)(b * NCHUNK + c) * D_INNER + (ds >> 4)];
        hin = e + exp2f(Af * sd) * hin;
    }
}

// ---- pass C: full scan from h_in, fused +u*D and *silu(z), write y (bf16) ----
__global__ __launch_bounds__(256)
void scan_partC(const float* __restrict__ delta, const u16* __restrict__ u,
                const float* __restrict__ xdbc, const float* __restrict__ z,
                const float* __restrict__ A_log, const float* __restrict__ Dp,
                const float* __restrict__ hbuf, u16* __restrict__ y)
{
    const int d = blockIdx.x * 256 + threadIdx.x;
    const int c = blockIdx.y;
    const int b = blockIdx.z;
    const int t0 = c * CHUNK_T;

    float Af[16];
    #pragma unroll
    for (int s = 0; s < 16; s++) Af[s] = -__expf(A_log[d * 16 + s]) * LOG2E;
    const float Dd = Dp[d];

    float h[16];
    const float* hin = hbuf + ((long)(b * NCHUNK + c) * D_INNER + d) * 16;
    #pragma unroll
    for (int s = 0; s < 16; s++) h[s] = hin[s];

    const float* dptr = delta + ((long)b * SEQ + t0) * D_INNER + d;
    const u16*   uptr = u     + ((long)b * SEQ + t0) * D_INNER + d;
    const float* zptr = z     + ((long)b * SEQ + t0) * D_INNER + d;
    const float* xp   = xdbc  + ((long)b * SEQ + t0) * XPROJ_N;
    u16* yptr = y + ((long)b * SEQ + t0) * D_INNER + d;

    for (int t = 0; t < CHUNK_T; t++) {
        float dl = dptr[(long)t * D_INNER];
        float uu = bf2f(uptr[(long)t * D_INNER]);
        float zl = zptr[(long)t * D_INNER];
        f32x4 B0 = *(const f32x4*)(xp + t * XPROJ_N + DT_RANK);
        f32x4 B1 = *(const f32x4*)(xp + t * XPROJ_N + DT_RANK + 4);
        f32x4 B2 = *(const f32x4*)(xp + t * XPROJ_N + DT_RANK + 8);
        f32x4 B3 = *(const f32x4*)(xp + t * XPROJ_N + DT_RANK + 12);
        f32x4 C0 = *(const f32x4*)(xp + t * XPROJ_N + DT_RANK + 16);
        f32x4 C1 = *(const f32x4*)(xp + t * XPROJ_N + DT_RANK + 20);
        f32x4 C2 = *(const f32x4*)(xp + t * XPROJ_N + DT_RANK + 24);
        f32x4 C3 = *(const f32x4*)(xp + t * XPROJ_N + DT_RANK + 28);
        float Bv[16] = {B0[0],B0[1],B0[2],B0[3], B1[0],B1[1],B1[2],B1[3],
                        B2[0],B2[1],B2[2],B2[3], B3[0],B3[1],B3[2],B3[3]};
        float Cv[16] = {C0[0],C0[1],C0[2],C0[3], C1[0],C1[1],C1[2],C1[3],
                        C2[0],C2[1],C2[2],C2[3], C3[0],C3[1],C3[2],C3[3]};
        float dlu = dl * uu;
        float p0 = 0.f, p1 = 0.f, p2 = 0.f, p3 = 0.f;
        #pragma unroll
        for (int s = 0; s < 16; s += 4) {
            h[s]   = h[s]   * exp2f(dl * Af[s])   + dlu * Bv[s];
            h[s+1] = h[s+1] * exp2f(dl * Af[s+1]) + dlu * Bv[s+1];
            h[s+2] = h[s+2] * exp2f(dl * Af[s+2]) + dlu * Bv[s+2];
            h[s+3] = h[s+3] * exp2f(dl * Af[s+3]) + dlu * Bv[s+3];
            p0 += h[s]   * Cv[s];
            p1 += h[s+1] * Cv[s+1];
            p2 += h[s+2] * Cv[s+2];
            p3 += h[s+3] * Cv[s+3];
        }
        float acc = (p0 + p1) + (p2 + p3);
        float sz = zl / (1.f + __expf(-zl));
        float yy = (acc + uu * Dd) * sz;
        yptr[(long)t * D_INNER] = f2bf(yy);
    }
}

__global__ __launch_bounds__(256)
void layernorm_kernel(const float* __restrict__ pre, const float* __restrict__ gamma,
                      const float* __restrict__ beta, float* __restrict__ out)
{
    const long row = blockIdx.x;
    const float* p = pre + row * DIM;
    int tid = threadIdx.x;
    float v[4];
    float sum = 0.f, sq = 0.f;
    #pragma unroll
    for (int i = 0; i < 4; i++) {
        v[i] = p[tid + i * 256];
        sum += v[i];
        sq  += v[i] * v[i];
    }
    #pragma unroll
    for (int off = 1; off < 64; off <<= 1) {
        sum += __shfl_xor(sum, off);
        sq  += __shfl_xor(sq, off);
    }
    __shared__ float ssum[4], ssq[4];
    int w = tid >> 6;
    if ((tid & 63) == 0) { ssum[w] = sum; ssq[w] = sq; }
    __syncthreads();
    float ts = ssum[0] + ssum[1] + ssum[2] + ssum[3];
    float tq = ssq[0] + ssq[1] + ssq[2] + ssq[3];
    float mean = ts * (1.f / DIM);
    float var  = tq * (1.f / DIM) - mean * mean;
    float rstd = rsqrtf(var + 1e-5f);
    float* o = out + row * DIM;
    #pragma unroll
    for (int i = 0; i < 4; i++) {
        int c = tid + i * 256;
        o[c] = (v[i] - mean) * rstd * gamma[c] + beta[c];
    }
}

extern "C" void kernel_launch(void* const* d_in, const int* in_sizes, int n_in,
                              void* d_out, int out_size, void* d_ws, size_t ws_size,
                              hipStream_t stream)
{
    const float* x      = (const float*)d_in[0];
    const float* W_in   = (const float*)d_in[1];
    const float* conv_w = (const float*)d_in[2];
    const float* conv_b = (const float*)d_in[3];
    const float* W_xproj= (const float*)d_in[4];
    const float* W_dt   = (const float*)d_in[5];
    const float* b_dt   = (const float*)d_in[6];
    const float* A_log  = (const float*)d_in[7];
    const float* Dv     = (const float*)d_in[8];
    const float* W_out  = (const float*)d_in[9];
    const float* gamma  = (const float*)d_in[10];
    const float* beta   = (const float*)d_in[11];

    char* ws = (char*)d_ws;
    // [0, 16M): xc bf16 (steps 1-2); then small splits + hbuf/sdel
    u16*   xc    = (u16*)(ws);
    u16*   xdh   = (u16*)(ws);                   // xdbc hi  (after gemm3)
    u16*   xdl   = (u16*)(ws + 786432);          // xdbc lo
    u16*   wxh   = (u16*)(ws + 1572864);         // W_xproj hi (after conv)
    u16*   wxl   = (u16*)(ws + 1966080);
    u16*   wdth  = (u16*)(ws + 2359296);         // W_dt hi
    u16*   wdtl  = (u16*)(ws + 2621440);
    float* hbuf  = (float*)(ws);                 // 8 MB  (scan, after gemm2)
    float* sdel  = (float*)(ws + 8388608);       // 0.5 MB
    // [16M, 48M): z f32; lower half later opre, upper half later W_out splits
    float* z     = (float*)(ws + 16777216);
    float* opre  = (float*)(ws + 16777216);
    u16*   wouth = (u16*)(ws + 33554432);        // after scanC
    u16*   woutl = (u16*)(ws + 37748736);
    // [48M, 64M): u bf16
    u16*   u     = (u16*)(ws + 50331648);
    // [64M, 96M): GEMM1 splits (steps 0-1), then delta f32 (step 4+)
    u16*   xh    = (u16*)(ws + 67108864);
    u16*   xl    = (u16*)(ws + 75497472);
    u16*   wh    = (u16*)(ws + 83886080);
    u16*   wl    = (u16*)(ws + 92274688);
    float* delta = (float*)(ws + 67108864);
    // [96M, 97.5M): xdbc f32
    float* xdbc  = (float*)(ws + 100663296);
    u16*   yb    = (u16*)d_out;                  // y staged in d_out

    // 0) pre-split GEMM1 operands
    split_kernel<<<16384, 256, 0, stream>>>(x, xh, xl, 4194304);
    split_kernel<<<16384, 256, 0, stream>>>(W_in, wh, wl, 4194304);
    // 1) xz = x @ W_in^T -> xc bf16 | z f32   (M=4096,N=4096,K=1024)
    gemm64<3, EPI_XZ><<<dim3(64, 64), 64, 0, stream>>>(
        xh, xl, DIM, wh, wl, DIM, xc, z, 0, DIM, nullptr);
    // 2) u = silu(conv4(xc)+cb)
    conv_silu<<<32768, 256, 0, stream>>>(xc, conv_w, conv_b, u);
    // 2b) small weight splits (into dead xc region)
    split_kernel<<<768, 256, 0, stream>>>(W_xproj, wxh, wxl, 196608);
    split_kernel<<<512, 256, 0, stream>>>(W_dt, wdth, wdtl, 131072);
    // 3) xdbc = u @ W_xproj^T  (split-K=8, atomic f32)
    zero_kernel<<<1536, 256, 0, stream>>>(xdbc, 393216);
    gemm3_splitk<<<dim3(3, 128, 8), 64, 0, stream>>>(
        u, D_INNER, wxh, wxl, D_INNER, xdbc, XPROJ_N, 256);
    // 3b) split xdbc for GEMM2's A operand
    split_kernel<<<1536, 256, 0, stream>>>(xdbc, xdh, xdl, 393216);
    // 4) delta = softplus(dt @ W_dt^T + b_dt)  (M=4096,N=2048,K=64) -> f32
    gemm64<3, EPI_SOFTPLUS><<<dim3(32, 64), 64, 0, stream>>>(
        xdh, xdl, XPROJ_N, wdth, wdtl, DT_RANK, delta, nullptr, D_INNER, DT_RANK, b_dt);
    // 5) chunked parallel scan
    scan_partA<<<dim3(8, NCHUNK, BSZ), 256, 0, stream>>>(delta, u, xdbc, A_log, hbuf, sdel);
    scan_fixup<<<256, 256, 0, stream>>>(hbuf, sdel, A_log);
    scan_partC<<<dim3(8, NCHUNK, BSZ), 256, 0, stream>>>(delta, u, xdbc, z, A_log, Dv, hbuf, yb);
    // 5b) split W_out (into dead z upper half)
    split_kernel<<<8192, 256, 0, stream>>>(W_out, wouth, woutl, 2097152);
    // 6) opre = yb @ W_out^T  (M=4096,N=1024,K=2048) -> f32
    gemm64<2, EPI_F32><<<dim3(16, 64), 64, 0, stream>>>(
        yb, nullptr, D_INNER, wouth, woutl, D_INNER, opre, nullptr, DIM, D_INNER, nullptr);
    // 7) layernorm -> d_out f32
    layernorm_kernel<<<4096, 256, 0, stream>>>(opre, gamma, beta, (float*)d_out);
}

// Round 6
// 581.974 us; speedup vs baseline: 2.6387x; 1.1787x over previous
//
#include <hip/hip_runtime.h>
#include <stdint.h>

typedef unsigned short u16;
typedef __bf16 bf16x8 __attribute__((ext_vector_type(8)));
typedef float f32x4 __attribute__((ext_vector_type(4)));

#define BSZ 2
#define SEQ 2048
#define DIM 1024
#define D_INNER 2048
#define DT_RANK 64
#define D_STATE 16
#define XPROJ_N 96   // DT_RANK + 2*D_STATE
#define NCHUNK 32
#define CHUNK_T 64   // SEQ / NCHUNK
#define LOG2E 1.44269504f

__device__ __forceinline__ float bf2f(u16 h) {
    return __uint_as_float(((unsigned)h) << 16);
}
__device__ __forceinline__ u16 f2bf(float f) {
    unsigned u = __float_as_uint(f);
    unsigned r = (u + 0x7FFFu + ((u >> 16) & 1u)) >> 16;
    return (u16)r;
}

__device__ __forceinline__ f32x4 mfma16(bf16x8 a, bf16x8 b, f32x4 c) {
    return __builtin_amdgcn_mfma_f32_16x16x32_bf16(a, b, c, 0, 0, 0);
}

// async global->LDS, 16B per lane. LDS dest = wave-uniform base + lane*16,
// so the staging order must be lane-contiguous (it is: chunk = w*64+lane).
__device__ __forceinline__ void gload_lds16(const void* g, void* l) {
    __builtin_amdgcn_global_load_lds(
        (const __attribute__((address_space(1))) unsigned int*)(uintptr_t)g,
        (__attribute__((address_space(3))) unsigned int*)(uintptr_t)l,
        16, 0, 0);
}

// f32 -> bf16 hi + bf16 lo (residual), one pass over the array
__global__ __launch_bounds__(256)
void split_kernel(const float* __restrict__ in, u16* __restrict__ hi,
                  u16* __restrict__ lo, int n)
{
    int i = blockIdx.x * 256 + threadIdx.x;
    if (i < n) {
        float v = in[i];
        u16 h = f2bf(v);
        hi[i] = h;
        lo[i] = f2bf(v - bf2f(h));
    }
}

__global__ __launch_bounds__(256)
void zero_kernel(float* __restrict__ p, int n)
{
    int i = blockIdx.x * 256 + threadIdx.x;
    if (i < n) p[i] = 0.f;
}

enum { EPI_XZ = 0, EPI_F32 = 1, EPI_SOFTPLUS = 2 };

// C[M,N] = (Ah+Al)[M,K] @ (Bh+Bl)[N,K]^T with bf16 hi/lo split operands.
// 128x128 tile per 256-thread block (4 waves, 2x2 of 64x64), BK=32,
// global_load_lds(16B) staging, swizzled LDS to kill ds_read_b128 conflicts.
// TERMS=3: ah*bh + ah*bl + al*bh.  TERMS=2 (A bf16 only): a*bh + a*bl.
template<int TERMS, int EPI>
__global__ __launch_bounds__(256)
void gemm128(const u16* __restrict__ Ah, const u16* __restrict__ Al, int lda,
             const u16* __restrict__ Bh, const u16* __restrict__ Bl, int ldb,
             void* __restrict__ C, void* __restrict__ C2, int ldc,
             int K, const float* __restrict__ bias)
{
    __shared__ u16 lds[(TERMS == 3) ? 16384 : 12288];
    u16* Ah_l = lds;
    u16* Al_l = lds + 4096;                              // TERMS==3 only
    u16* Bh_l = lds + ((TERMS == 3) ? 8192 : 4096);
    u16* Bl_l = lds + ((TERMS == 3) ? 12288 : 8192);

    const int tid  = threadIdx.x;
    const int w    = tid >> 6;
    const int lane = tid & 63;
    const int r16  = lane & 15;
    const int quad = lane >> 4;
    const int wr   = w >> 1;          // wave row (0..1)
    const int wc   = w & 1;           // wave col (0..1)
    const long m0  = (long)blockIdx.y * 128;
    const long n0  = (long)blockIdx.x * 128;

    // staging chunks: 512 16B-chunks per tile; this thread does c0 and c1.
    // chunk c holds global (m = c>>2, kc = (c&3) ^ ((m>>1)&3)) -> 2-way-only
    // bank aliasing for the ds_read_b128 fragment reads below.
    const int c0 = w * 64 + lane;
    const int c1 = 256 + c0;
    const int ma0 = c0 >> 2, kca0 = ((c0 & 3) ^ ((ma0 >> 1) & 3)) * 8;
    const int ma1 = c1 >> 2, kca1 = ((c1 & 3) ^ ((ma1 >> 1) & 3)) * 8;

    const u16* Arow0 = Ah + (m0 + ma0) * (long)lda + kca0;
    const u16* Arow1 = Ah + (m0 + ma1) * (long)lda + kca1;
    const u16* Alrow0 = (TERMS == 3) ? Al + (m0 + ma0) * (long)lda + kca0 : nullptr;
    const u16* Alrow1 = (TERMS == 3) ? Al + (m0 + ma1) * (long)lda + kca1 : nullptr;
    const u16* Brow0 = Bh + (n0 + ma0) * (long)ldb + kca0;
    const u16* Brow1 = Bh + (n0 + ma1) * (long)ldb + kca1;
    const u16* Blrow0 = Bl + (n0 + ma0) * (long)ldb + kca0;
    const u16* Blrow1 = Bl + (n0 + ma1) * (long)ldb + kca1;

    f32x4 acc[4][4];
    #pragma unroll
    for (int i = 0; i < 4; i++)
        #pragma unroll
        for (int j = 0; j < 4; j++) acc[i][j] = {0.f, 0.f, 0.f, 0.f};

    // fragment LDS chunk offsets (u16 units), same swizzle as staging
    int caof[4], cbof[4];
    #pragma unroll
    for (int i = 0; i < 4; i++) {
        int m = wr * 64 + i * 16 + r16;
        caof[i] = (m * 4 + (quad ^ ((m >> 1) & 3))) * 8;
        int n = wc * 64 + i * 16 + r16;
        cbof[i] = (n * 4 + (quad ^ ((n >> 1) & 3))) * 8;
    }

    for (int k0 = 0; k0 < K; k0 += 32) {
        __syncthreads();
        gload_lds16(Arow0 + k0, Ah_l + c0 * 8);
        gload_lds16(Arow1 + k0, Ah_l + c1 * 8);
        if (TERMS == 3) {
            gload_lds16(Alrow0 + k0, Al_l + c0 * 8);
            gload_lds16(Alrow1 + k0, Al_l + c1 * 8);
        }
        gload_lds16(Brow0 + k0, Bh_l + c0 * 8);
        gload_lds16(Brow1 + k0, Bh_l + c1 * 8);
        gload_lds16(Blrow0 + k0, Bl_l + c0 * 8);
        gload_lds16(Blrow1 + k0, Bl_l + c1 * 8);
        __syncthreads();

        bf16x8 fah[4], fal[4], fbh[4], fbl[4];
        #pragma unroll
        for (int i = 0; i < 4; i++) {
            fah[i] = *(const bf16x8*)(Ah_l + caof[i]);
            if (TERMS == 3) fal[i] = *(const bf16x8*)(Al_l + caof[i]);
            fbh[i] = *(const bf16x8*)(Bh_l + cbof[i]);
            fbl[i] = *(const bf16x8*)(Bl_l + cbof[i]);
        }
        #pragma unroll
        for (int i = 0; i < 4; i++) {
            #pragma unroll
            for (int j = 0; j < 4; j++) {
                acc[i][j] = mfma16(fah[i], fbh[j], acc[i][j]);
                acc[i][j] = mfma16(fah[i], fbl[j], acc[i][j]);
                if (TERMS == 3) acc[i][j] = mfma16(fal[i], fbh[j], acc[i][j]);
            }
        }
    }

    #pragma unroll
    for (int i = 0; i < 4; i++) {
        #pragma unroll
        for (int j = 0; j < 4; j++) {
            long col = n0 + wc * 64 + j * 16 + r16;
            #pragma unroll
            for (int r = 0; r < 4; r++) {
                long row = m0 + wr * 64 + i * 16 + quad * 4 + r;
                float x = acc[i][j][r];
                if (EPI == EPI_XZ) {
                    if (col < D_INNER) ((u16*)C)[row * (long)D_INNER + col] = f2bf(x);
                    else ((float*)C2)[row * (long)D_INNER + (col - D_INNER)] = x;
                } else if (EPI == EPI_SOFTPLUS) {
                    x += bias[col];
                    x = (x > 15.f) ? x : log1pf(__expf(x));
                    ((float*)C)[row * (long)ldc + col] = x;
                } else {
                    ((float*)C)[row * (long)ldc + col] = x;
                }
            }
        }
    }
}

// GEMM3: xdbc += u @ W_xproj^T, split-K over blockIdx.z, 32x32 tile per wave
__global__ __launch_bounds__(64)
void gemm3_splitk(const u16* __restrict__ A, int lda,
                  const u16* __restrict__ Bh, const u16* __restrict__ Bl, int ldb,
                  float* __restrict__ C, int ldc, int K0)
{
    const int lane = threadIdx.x;
    const int r16  = lane & 15;
    const int quad = lane >> 4;
    const long m0 = (long)blockIdx.y * 32;
    const long n0 = (long)blockIdx.x * 32;
    const int kbase = blockIdx.z * K0;

    const u16* Ap0 = A  + (m0 + r16) * (long)lda + quad * 8 + kbase;
    const u16* Ap1 = Ap0 + 16L * lda;
    const u16* Bh0 = Bh + (n0 + r16) * (long)ldb + quad * 8 + kbase;
    const u16* Bh1 = Bh0 + 16L * ldb;
    const u16* Bl0 = Bl + (n0 + r16) * (long)ldb + quad * 8 + kbase;
    const u16* Bl1 = Bl0 + 16L * ldb;

    f32x4 acc00 = {0,0,0,0}, acc01 = {0,0,0,0}, acc10 = {0,0,0,0}, acc11 = {0,0,0,0};

    for (int k = 0; k < K0; k += 32) {
        bf16x8 a0 = *(const bf16x8*)(Ap0 + k);
        bf16x8 a1 = *(const bf16x8*)(Ap1 + k);
        bf16x8 b0h = *(const bf16x8*)(Bh0 + k);
        bf16x8 b1h = *(const bf16x8*)(Bh1 + k);
        bf16x8 b0l = *(const bf16x8*)(Bl0 + k);
        bf16x8 b1l = *(const bf16x8*)(Bl1 + k);
        acc00 = mfma16(a0, b0h, acc00); acc00 = mfma16(a0, b0l, acc00);
        acc01 = mfma16(a0, b1h, acc01); acc01 = mfma16(a0, b1l, acc01);
        acc10 = mfma16(a1, b0h, acc10); acc10 = mfma16(a1, b0l, acc10);
        acc11 = mfma16(a1, b1h, acc11); acc11 = mfma16(a1, b1l, acc11);
    }

    #pragma unroll
    for (int i = 0; i < 2; i++) {
        #pragma unroll
        for (int j = 0; j < 2; j++) {
            f32x4 v = (i == 0) ? (j == 0 ? acc00 : acc01) : (j == 0 ? acc10 : acc11);
            long col = n0 + j * 16 + r16;
            #pragma unroll
            for (int r = 0; r < 4; r++) {
                long row = m0 + i * 16 + quad * 4 + r;
                atomicAdd(&C[row * (long)ldc + col], v[r]);
            }
        }
    }
}

// depthwise causal conv(4) + bias + silu : xc (bf16 [4096,2048]) -> u (bf16)
__global__ __launch_bounds__(256)
void conv_silu(const u16* __restrict__ xc, const float* __restrict__ cw,
               const float* __restrict__ cb, u16* __restrict__ u)
{
    int idx = blockIdx.x * 256 + threadIdx.x;   // (b*2048+t)*2048 + d
    int d = idx & 2047;
    int t = (idx >> 11) & 2047;
    float acc = cb[d];
    #pragma unroll
    for (int j = 0; j < 4; j++) {
        int tt = t - 3 + j;
        if (tt >= 0) acc += cw[d * 4 + j] * bf2f(xc[idx + (long)(j - 3) * D_INNER]);
    }
    float s = acc / (1.f + __expf(-acc));
    u[idx] = f2bf(s);
}

// ---- chunked parallel scan: pass A ----
__global__ __launch_bounds__(256)
void scan_partA(const float* __restrict__ delta, const u16* __restrict__ u,
                const float* __restrict__ xdbc, const float* __restrict__ A_log,
                float* __restrict__ hbuf, float* __restrict__ sdelta)
{
    const int d = blockIdx.x * 256 + threadIdx.x;
    const int c = blockIdx.y;
    const int b = blockIdx.z;
    const int t0 = c * CHUNK_T;

    float Af[16];
    #pragma unroll
    for (int s = 0; s < 16; s++) Af[s] = -__expf(A_log[d * 16 + s]) * LOG2E;

    float h[16];
    #pragma unroll
    for (int s = 0; s < 16; s++) h[s] = 0.f;
    float sd = 0.f;

    const float* dptr = delta + ((long)b * SEQ + t0) * D_INNER + d;
    const u16*   uptr = u     + ((long)b * SEQ + t0) * D_INNER + d;
    const float* xp   = xdbc  + ((long)b * SEQ + t0) * XPROJ_N;

    for (int t = 0; t < CHUNK_T; t++) {
        float dl = dptr[(long)t * D_INNER];
        float uu = bf2f(uptr[(long)t * D_INNER]);
        f32x4 B0 = *(const f32x4*)(xp + t * XPROJ_N + DT_RANK);
        f32x4 B1 = *(const f32x4*)(xp + t * XPROJ_N + DT_RANK + 4);
        f32x4 B2 = *(const f32x4*)(xp + t * XPROJ_N + DT_RANK + 8);
        f32x4 B3 = *(const f32x4*)(xp + t * XPROJ_N + DT_RANK + 12);
        float Bv[16] = {B0[0],B0[1],B0[2],B0[3], B1[0],B1[1],B1[2],B1[3],
                        B2[0],B2[1],B2[2],B2[3], B3[0],B3[1],B3[2],B3[3]};
        sd += dl;
        float dlu = dl * uu;
        #pragma unroll
        for (int s = 0; s < 16; s++)
            h[s] = h[s] * exp2f(dl * Af[s]) + dlu * Bv[s];
    }

    float* hout = hbuf + ((long)(b * NCHUNK + c) * D_INNER + d) * 16;
    #pragma unroll
    for (int s = 0; s < 16; s++) hout[s] = h[s];
    sdelta[(long)(b * NCHUNK + c) * D_INNER + d] = sd;
}

// ---- pass B: compose chunk boundaries (in-place: hbuf h_end -> h_in) ----
__global__ __launch_bounds__(256)
void scan_fixup(float* __restrict__ hbuf, const float* __restrict__ sdelta,
                const float* __restrict__ A_log)
{
    const int idx = blockIdx.x * 256 + threadIdx.x;   // 65536 threads
    const int ds = idx & (D_INNER * 16 - 1);
    const int b  = idx >> 15;
    const float Af = -__expf(A_log[ds]) * LOG2E;
    float hin = 0.f;
    #pragma unroll 4
    for (int c = 0; c < NCHUNK; c++) {
        long gi = (long)(b * NCHUNK + c) * (D_INNER * 16) + ds;
        float e = hbuf[gi];
        hbuf[gi] = hin;
        float sd = sdelta[(long)(b * NCHUNK + c) * D_INNER + (ds >> 4)];
        hin = e + exp2f(Af * sd) * hin;
    }
}

// ---- pass C: full scan from h_in, fused +u*D and *silu(z), write y (bf16) ----
__global__ __launch_bounds__(256)
void scan_partC(const float* __restrict__ delta, const u16* __restrict__ u,
                const float* __restrict__ xdbc, const float* __restrict__ z,
                const float* __restrict__ A_log, const float* __restrict__ Dp,
                const float* __restrict__ hbuf, u16* __restrict__ y)
{
    const int d = blockIdx.x * 256 + threadIdx.x;
    const int c = blockIdx.y;
    const int b = blockIdx.z;
    const int t0 = c * CHUNK_T;

    float Af[16];
    #pragma unroll
    for (int s = 0; s < 16; s++) Af[s] = -__expf(A_log[d * 16 + s]) * LOG2E;
    const float Dd = Dp[d];

    float h[16];
    const float* hin = hbuf + ((long)(b * NCHUNK + c) * D_INNER + d) * 16;
    #pragma unroll
    for (int s = 0; s < 16; s++) h[s] = hin[s];

    const float* dptr = delta + ((long)b * SEQ + t0) * D_INNER + d;
    const u16*   uptr = u     + ((long)b * SEQ + t0) * D_INNER + d;
    const float* zptr = z     + ((long)b * SEQ + t0) * D_INNER + d;
    const float* xp   = xdbc  + ((long)b * SEQ + t0) * XPROJ_N;
    u16* yptr = y + ((long)b * SEQ + t0) * D_INNER + d;

    for (int t = 0; t < CHUNK_T; t++) {
        float dl = dptr[(long)t * D_INNER];
        float uu = bf2f(uptr[(long)t * D_INNER]);
        float zl = zptr[(long)t * D_INNER];
        f32x4 B0 = *(const f32x4*)(xp + t * XPROJ_N + DT_RANK);
        f32x4 B1 = *(const f32x4*)(xp + t * XPROJ_N + DT_RANK + 4);
        f32x4 B2 = *(const f32x4*)(xp + t * XPROJ_N + DT_RANK + 8);
        f32x4 B3 = *(const f32x4*)(xp + t * XPROJ_N + DT_RANK + 12);
        f32x4 C0 = *(const f32x4*)(xp + t * XPROJ_N + DT_RANK + 16);
        f32x4 C1 = *(const f32x4*)(xp + t * XPROJ_N + DT_RANK + 20);
        f32x4 C2 = *(const f32x4*)(xp + t * XPROJ_N + DT_RANK + 24);
        f32x4 C3 = *(const f32x4*)(xp + t * XPROJ_N + DT_RANK + 28);
        float Bv[16] = {B0[0],B0[1],B0[2],B0[3], B1[0],B1[1],B1[2],B1[3],
                        B2[0],B2[1],B2[2],B2[3], B3[0],B3[1],B3[2],B3[3]};
        float Cv[16] = {C0[0],C0[1],C0[2],C0[3], C1[0],C1[1],C1[2],C1[3],
                        C2[0],C2[1],C2[2],C2[3], C3[0],C3[1],C3[2],C3[3]};
        float dlu = dl * uu;
        float p0 = 0.f, p1 = 0.f, p2 = 0.f, p3 = 0.f;
        #pragma unroll
        for (int s = 0; s < 16; s += 4) {
            h[s]   = h[s]   * exp2f(dl * Af[s])   + dlu * Bv[s];
            h[s+1] = h[s+1] * exp2f(dl * Af[s+1]) + dlu * Bv[s+1];
            h[s+2] = h[s+2] * exp2f(dl * Af[s+2]) + dlu * Bv[s+2];
            h[s+3] = h[s+3] * exp2f(dl * Af[s+3]) + dlu * Bv[s+3];
            p0 += h[s]   * Cv[s];
            p1 += h[s+1] * Cv[s+1];
            p2 += h[s+2] * Cv[s+2];
            p3 += h[s+3] * Cv[s+3];
        }
        float acc = (p0 + p1) + (p2 + p3);
        float sz = zl / (1.f + __expf(-zl));
        float yy = (acc + uu * Dd) * sz;
        yptr[(long)t * D_INNER] = f2bf(yy);
    }
}

__global__ __launch_bounds__(256)
void layernorm_kernel(const float* __restrict__ pre, const float* __restrict__ gamma,
                      const float* __restrict__ beta, float* __restrict__ out)
{
    const long row = blockIdx.x;
    const float* p = pre + row * DIM;
    int tid = threadIdx.x;
    float v[4];
    float sum = 0.f, sq = 0.f;
    #pragma unroll
    for (int i = 0; i < 4; i++) {
        v[i] = p[tid + i * 256];
        sum += v[i];
        sq  += v[i] * v[i];
    }
    #pragma unroll
    for (int off = 1; off < 64; off <<= 1) {
        sum += __shfl_xor(sum, off);
        sq  += __shfl_xor(sq, off);
    }
    __shared__ float ssum[4], ssq[4];
    int w = tid >> 6;
    if ((tid & 63) == 0) { ssum[w] = sum; ssq[w] = sq; }
    __syncthreads();
    float ts = ssum[0] + ssum[1] + ssum[2] + ssum[3];
    float tq = ssq[0] + ssq[1] + ssq[2] + ssq[3];
    float mean = ts * (1.f / DIM);
    float var  = tq * (1.f / DIM) - mean * mean;
    float rstd = rsqrtf(var + 1e-5f);
    float* o = out + row * DIM;
    #pragma unroll
    for (int i = 0; i < 4; i++) {
        int c = tid + i * 256;
        o[c] = (v[i] - mean) * rstd * gamma[c] + beta[c];
    }
}

extern "C" void kernel_launch(void* const* d_in, const int* in_sizes, int n_in,
                              void* d_out, int out_size, void* d_ws, size_t ws_size,
                              hipStream_t stream)
{
    const float* x      = (const float*)d_in[0];
    const float* W_in   = (const float*)d_in[1];
    const float* conv_w = (const float*)d_in[2];
    const float* conv_b = (const float*)d_in[3];
    const float* W_xproj= (const float*)d_in[4];
    const float* W_dt   = (const float*)d_in[5];
    const float* b_dt   = (const float*)d_in[6];
    const float* A_log  = (const float*)d_in[7];
    const float* Dv     = (const float*)d_in[8];
    const float* W_out  = (const float*)d_in[9];
    const float* gamma  = (const float*)d_in[10];
    const float* beta   = (const float*)d_in[11];

    char* ws = (char*)d_ws;
    // [0, 16M): xc bf16 (steps 1-2); then small splits + hbuf/sdel
    u16*   xc    = (u16*)(ws);
    u16*   xdh   = (u16*)(ws);                   // xdbc hi  (after gemm3)
    u16*   xdl   = (u16*)(ws + 786432);          // xdbc lo
    u16*   wxh   = (u16*)(ws + 1572864);         // W_xproj hi (after conv)
    u16*   wxl   = (u16*)(ws + 1966080);
    u16*   wdth  = (u16*)(ws + 2359296);         // W_dt hi
    u16*   wdtl  = (u16*)(ws + 2621440);
    float* hbuf  = (float*)(ws);                 // 8 MB  (scan, after gemm2)
    float* sdel  = (float*)(ws + 8388608);       // 0.5 MB
    // [16M, 48M): z f32; lower half later opre, upper half later W_out splits
    float* z     = (float*)(ws + 16777216);
    float* opre  = (float*)(ws + 16777216);
    u16*   wouth = (u16*)(ws + 33554432);        // after scanC
    u16*   woutl = (u16*)(ws + 37748736);
    // [48M, 64M): u bf16
    u16*   u     = (u16*)(ws + 50331648);
    // [64M, 96M): GEMM1 splits (steps 0-1), then delta f32 (step 4+)
    u16*   xh    = (u16*)(ws + 67108864);
    u16*   xl    = (u16*)(ws + 75497472);
    u16*   wh    = (u16*)(ws + 83886080);
    u16*   wl    = (u16*)(ws + 92274688);
    float* delta = (float*)(ws + 67108864);
    // [96M, 97.5M): xdbc f32
    float* xdbc  = (float*)(ws + 100663296);
    u16*   yb    = (u16*)d_out;                  // y staged in d_out

    // 0) pre-split GEMM1 operands
    split_kernel<<<16384, 256, 0, stream>>>(x, xh, xl, 4194304);
    split_kernel<<<16384, 256, 0, stream>>>(W_in, wh, wl, 4194304);
    // 1) xz = x @ W_in^T -> xc bf16 | z f32   (M=4096,N=4096,K=1024)
    gemm128<3, EPI_XZ><<<dim3(32, 32), 256, 0, stream>>>(
        xh, xl, DIM, wh, wl, DIM, xc, z, 0, DIM, nullptr);
    // 2) u = silu(conv4(xc)+cb)
    conv_silu<<<32768, 256, 0, stream>>>(xc, conv_w, conv_b, u);
    // 2b) small weight splits (into dead xc region)
    split_kernel<<<768, 256, 0, stream>>>(W_xproj, wxh, wxl, 196608);
    split_kernel<<<512, 256, 0, stream>>>(W_dt, wdth, wdtl, 131072);
    // 3) xdbc = u @ W_xproj^T  (split-K=8, atomic f32)
    zero_kernel<<<1536, 256, 0, stream>>>(xdbc, 393216);
    gemm3_splitk<<<dim3(3, 128, 8), 64, 0, stream>>>(
        u, D_INNER, wxh, wxl, D_INNER, xdbc, XPROJ_N, 256);
    // 3b) split xdbc for GEMM2's A operand
    split_kernel<<<1536, 256, 0, stream>>>(xdbc, xdh, xdl, 393216);
    // 4) delta = softplus(dt @ W_dt^T + b_dt)  (M=4096,N=2048,K=64) -> f32
    gemm128<3, EPI_SOFTPLUS><<<dim3(16, 32), 256, 0, stream>>>(
        xdh, xdl, XPROJ_N, wdth, wdtl, DT_RANK, delta, nullptr, D_INNER, DT_RANK, b_dt);
    // 5) chunked parallel scan
    scan_partA<<<dim3(8, NCHUNK, BSZ), 256, 0, stream>>>(delta, u, xdbc, A_log, hbuf, sdel);
    scan_fixup<<<256, 256, 0, stream>>>(hbuf, sdel, A_log);
    scan_partC<<<dim3(8, NCHUNK, BSZ), 256, 0, stream>>>(delta, u, xdbc, z, A_log, Dv, hbuf, yb);
    // 5b) split W_out (into dead z upper half)
    split_kernel<<<8192, 256, 0, stream>>>(W_out, wouth, woutl, 2097152);
    // 6) opre = yb @ W_out^T  (M=4096,N=1024,K=2048) -> f32
    gemm128<2, EPI_F32><<<dim3(8, 32), 256, 0, stream>>>(
        yb, nullptr, D_INNER, wouth, woutl, D_INNER, opre, nullptr, DIM, D_INNER, nullptr);
    // 7) layernorm -> d_out f32
    layernorm_kernel<<<4096, 256, 0, stream>>>(opre, gamma, beta, (float*)d_out);
}

// Round 7
// 482.471 us; speedup vs baseline: 3.1829x; 1.2062x over previous
//
#include <hip/hip_runtime.h>
#include <stdint.h>

typedef unsigned short u16;
typedef __bf16 bf16x8 __attribute__((ext_vector_type(8)));
typedef unsigned short u16x8 __attribute__((ext_vector_type(8)));
typedef float f32x4 __attribute__((ext_vector_type(4)));

#define BSZ 2
#define SEQ 2048
#define DIM 1024
#define D_INNER 2048
#define DT_RANK 64
#define D_STATE 16
#define XPROJ_N 96   // DT_RANK + 2*D_STATE
#define NCHUNK 32
#define CHUNK_T 64   // SEQ / NCHUNK
#define LOG2E 1.44269504f

__device__ __forceinline__ float bf2f(u16 h) {
    return __uint_as_float(((unsigned)h) << 16);
}
__device__ __forceinline__ u16 f2bf(float f) {
    unsigned u = __float_as_uint(f);
    unsigned r = (u + 0x7FFFu + ((u >> 16) & 1u)) >> 16;
    return (u16)r;
}

__device__ __forceinline__ f32x4 mfma16(bf16x8 a, bf16x8 b, f32x4 c) {
    return __builtin_amdgcn_mfma_f32_16x16x32_bf16(a, b, c, 0, 0, 0);
}

__device__ __forceinline__ void gload_lds16(const void* g, void* l) {
    __builtin_amdgcn_global_load_lds(
        (const __attribute__((address_space(1))) unsigned int*)(uintptr_t)g,
        (__attribute__((address_space(3))) unsigned int*)(uintptr_t)l,
        16, 0, 0);
}

// split two f32 arrays -> bf16 hi/lo in one launch
__global__ __launch_bounds__(256)
void split2_kernel(const float* __restrict__ in0, u16* __restrict__ hi0,
                   u16* __restrict__ lo0, int n0,
                   const float* __restrict__ in1, u16* __restrict__ hi1,
                   u16* __restrict__ lo1, int n1)
{
    int i = blockIdx.x * 256 + threadIdx.x;
    if (i < n0) {
        float v = in0[i];
        u16 h = f2bf(v);
        hi0[i] = h;
        lo0[i] = f2bf(v - bf2f(h));
    } else {
        int j = i - n0;
        if (j < n1) {
            float v = in1[j];
            u16 h = f2bf(v);
            hi1[j] = h;
            lo1[j] = f2bf(v - bf2f(h));
        }
    }
}

__global__ __launch_bounds__(256)
void split_kernel(const float* __restrict__ in, u16* __restrict__ hi,
                  u16* __restrict__ lo, int n)
{
    int i = blockIdx.x * 256 + threadIdx.x;
    if (i < n) {
        float v = in[i];
        u16 h = f2bf(v);
        hi[i] = h;
        lo[i] = f2bf(v - bf2f(h));
    }
}

__global__ __launch_bounds__(256)
void zero_kernel(float* __restrict__ p, int n)
{
    int i = blockIdx.x * 256 + threadIdx.x;
    if (i < n) p[i] = 0.f;
}

enum { EPI_XZ = 0, EPI_F32 = 1, EPI_SOFTPLUS = 2 };

// 128x128 tile per 256-thread block, BK=32, global_load_lds staging, swizzled
// LDS. TERMS=3: ah*bh+ah*bl+al*bh. TERMS=2: a*bh+a*bl.
template<int TERMS, int EPI>
__global__ __launch_bounds__(256)
void gemm128(const u16* __restrict__ Ah, const u16* __restrict__ Al, int lda,
             const u16* __restrict__ Bh, const u16* __restrict__ Bl, int ldb,
             void* __restrict__ C, void* __restrict__ C2, int ldc,
             int K, const float* __restrict__ bias)
{
    __shared__ u16 lds[(TERMS == 3) ? 16384 : 12288];
    u16* Ah_l = lds;
    u16* Al_l = lds + 4096;
    u16* Bh_l = lds + ((TERMS == 3) ? 8192 : 4096);
    u16* Bl_l = lds + ((TERMS == 3) ? 12288 : 8192);

    const int tid  = threadIdx.x;
    const int w    = tid >> 6;
    const int lane = tid & 63;
    const int r16  = lane & 15;
    const int quad = lane >> 4;
    const int wr   = w >> 1;
    const int wc   = w & 1;
    const long m0  = (long)blockIdx.y * 128;
    const long n0  = (long)blockIdx.x * 128;

    const int c0 = w * 64 + lane;
    const int c1 = 256 + c0;
    const int ma0 = c0 >> 2, kca0 = ((c0 & 3) ^ ((ma0 >> 1) & 3)) * 8;
    const int ma1 = c1 >> 2, kca1 = ((c1 & 3) ^ ((ma1 >> 1) & 3)) * 8;

    const u16* Arow0 = Ah + (m0 + ma0) * (long)lda + kca0;
    const u16* Arow1 = Ah + (m0 + ma1) * (long)lda + kca1;
    const u16* Alrow0 = (TERMS == 3) ? Al + (m0 + ma0) * (long)lda + kca0 : nullptr;
    const u16* Alrow1 = (TERMS == 3) ? Al + (m0 + ma1) * (long)lda + kca1 : nullptr;
    const u16* Brow0 = Bh + (n0 + ma0) * (long)ldb + kca0;
    const u16* Brow1 = Bh + (n0 + ma1) * (long)ldb + kca1;
    const u16* Blrow0 = Bl + (n0 + ma0) * (long)ldb + kca0;
    const u16* Blrow1 = Bl + (n0 + ma1) * (long)ldb + kca1;

    f32x4 acc[4][4];
    #pragma unroll
    for (int i = 0; i < 4; i++)
        #pragma unroll
        for (int j = 0; j < 4; j++) acc[i][j] = {0.f, 0.f, 0.f, 0.f};

    int caof[4], cbof[4];
    #pragma unroll
    for (int i = 0; i < 4; i++) {
        int m = wr * 64 + i * 16 + r16;
        caof[i] = (m * 4 + (quad ^ ((m >> 1) & 3))) * 8;
        int n = wc * 64 + i * 16 + r16;
        cbof[i] = (n * 4 + (quad ^ ((n >> 1) & 3))) * 8;
    }

    for (int k0 = 0; k0 < K; k0 += 32) {
        __syncthreads();
        gload_lds16(Arow0 + k0, Ah_l + c0 * 8);
        gload_lds16(Arow1 + k0, Ah_l + c1 * 8);
        if (TERMS == 3) {
            gload_lds16(Alrow0 + k0, Al_l + c0 * 8);
            gload_lds16(Alrow1 + k0, Al_l + c1 * 8);
        }
        gload_lds16(Brow0 + k0, Bh_l + c0 * 8);
        gload_lds16(Brow1 + k0, Bh_l + c1 * 8);
        gload_lds16(Blrow0 + k0, Bl_l + c0 * 8);
        gload_lds16(Blrow1 + k0, Bl_l + c1 * 8);
        __syncthreads();

        bf16x8 fah[4], fal[4], fbh[4], fbl[4];
        #pragma unroll
        for (int i = 0; i < 4; i++) {
            fah[i] = *(const bf16x8*)(Ah_l + caof[i]);
            if (TERMS == 3) fal[i] = *(const bf16x8*)(Al_l + caof[i]);
            fbh[i] = *(const bf16x8*)(Bh_l + cbof[i]);
            fbl[i] = *(const bf16x8*)(Bl_l + cbof[i]);
        }
        #pragma unroll
        for (int i = 0; i < 4; i++) {
            #pragma unroll
            for (int j = 0; j < 4; j++) {
                acc[i][j] = mfma16(fah[i], fbh[j], acc[i][j]);
                acc[i][j] = mfma16(fah[i], fbl[j], acc[i][j]);
                if (TERMS == 3) acc[i][j] = mfma16(fal[i], fbh[j], acc[i][j]);
            }
        }
    }

    #pragma unroll
    for (int i = 0; i < 4; i++) {
        #pragma unroll
        for (int j = 0; j < 4; j++) {
            long col = n0 + wc * 64 + j * 16 + r16;
            #pragma unroll
            for (int r = 0; r < 4; r++) {
                long row = m0 + wr * 64 + i * 16 + quad * 4 + r;
                float x = acc[i][j][r];
                if (EPI == EPI_XZ) {
                    if (col < D_INNER) ((u16*)C)[row * (long)D_INNER + col] = f2bf(x);
                    else ((float*)C2)[row * (long)D_INNER + (col - D_INNER)] = x;
                } else if (EPI == EPI_SOFTPLUS) {
                    x += bias[col];
                    x = (x > 15.f) ? x : log1pf(__expf(x));
                    ((float*)C)[row * (long)ldc + col] = x;
                } else {
                    ((float*)C)[row * (long)ldc + col] = x;
                }
            }
        }
    }
}

// GEMM4 split-K: 128x128 tile, TERMS=2, kz slice -> its own f32 partial buffer
__global__ __launch_bounds__(256)
void gemm128_sk2(const u16* __restrict__ Ah, int lda,
                 const u16* __restrict__ Bh, const u16* __restrict__ Bl, int ldb,
                 float* __restrict__ OutA, float* __restrict__ OutB, int ldc, int K0)
{
    __shared__ u16 lds[12288];
    u16* Ah_l = lds;
    u16* Bh_l = lds + 4096;
    u16* Bl_l = lds + 8192;

    const int tid  = threadIdx.x;
    const int w    = tid >> 6;
    const int lane = tid & 63;
    const int r16  = lane & 15;
    const int quad = lane >> 4;
    const int wr   = w >> 1;
    const int wc   = w & 1;
    const long m0  = (long)blockIdx.y * 128;
    const long n0  = (long)blockIdx.x * 128;
    const int kz   = blockIdx.z;
    const int kbase = kz * K0;
    float* Out = (kz < 2) ? (OutA + (long)kz * 4194304)
                          : (OutB + (long)(kz - 2) * 4194304);

    const int c0 = w * 64 + lane;
    const int c1 = 256 + c0;
    const int ma0 = c0 >> 2, kca0 = ((c0 & 3) ^ ((ma0 >> 1) & 3)) * 8;
    const int ma1 = c1 >> 2, kca1 = ((c1 & 3) ^ ((ma1 >> 1) & 3)) * 8;

    const u16* Arow0 = Ah + (m0 + ma0) * (long)lda + kbase + kca0;
    const u16* Arow1 = Ah + (m0 + ma1) * (long)lda + kbase + kca1;
    const u16* Brow0 = Bh + (n0 + ma0) * (long)ldb + kbase + kca0;
    const u16* Brow1 = Bh + (n0 + ma1) * (long)ldb + kbase + kca1;
    const u16* Blrow0 = Bl + (n0 + ma0) * (long)ldb + kbase + kca0;
    const u16* Blrow1 = Bl + (n0 + ma1) * (long)ldb + kbase + kca1;

    f32x4 acc[4][4];
    #pragma unroll
    for (int i = 0; i < 4; i++)
        #pragma unroll
        for (int j = 0; j < 4; j++) acc[i][j] = {0.f, 0.f, 0.f, 0.f};

    int caof[4], cbof[4];
    #pragma unroll
    for (int i = 0; i < 4; i++) {
        int m = wr * 64 + i * 16 + r16;
        caof[i] = (m * 4 + (quad ^ ((m >> 1) & 3))) * 8;
        int n = wc * 64 + i * 16 + r16;
        cbof[i] = (n * 4 + (quad ^ ((n >> 1) & 3))) * 8;
    }

    for (int k0 = 0; k0 < K0; k0 += 32) {
        __syncthreads();
        gload_lds16(Arow0 + k0, Ah_l + c0 * 8);
        gload_lds16(Arow1 + k0, Ah_l + c1 * 8);
        gload_lds16(Brow0 + k0, Bh_l + c0 * 8);
        gload_lds16(Brow1 + k0, Bh_l + c1 * 8);
        gload_lds16(Blrow0 + k0, Bl_l + c0 * 8);
        gload_lds16(Blrow1 + k0, Bl_l + c1 * 8);
        __syncthreads();

        bf16x8 fah[4], fbh[4], fbl[4];
        #pragma unroll
        for (int i = 0; i < 4; i++) {
            fah[i] = *(const bf16x8*)(Ah_l + caof[i]);
            fbh[i] = *(const bf16x8*)(Bh_l + cbof[i]);
            fbl[i] = *(const bf16x8*)(Bl_l + cbof[i]);
        }
        #pragma unroll
        for (int i = 0; i < 4; i++) {
            #pragma unroll
            for (int j = 0; j < 4; j++) {
                acc[i][j] = mfma16(fah[i], fbh[j], acc[i][j]);
                acc[i][j] = mfma16(fah[i], fbl[j], acc[i][j]);
            }
        }
    }

    #pragma unroll
    for (int i = 0; i < 4; i++) {
        #pragma unroll
        for (int j = 0; j < 4; j++) {
            long col = n0 + wc * 64 + j * 16 + r16;
            #pragma unroll
            for (int r = 0; r < 4; r++) {
                long row = m0 + wr * 64 + i * 16 + quad * 4 + r;
                Out[row * (long)ldc + col] = acc[i][j][r];
            }
        }
    }
}

// GEMM2 (K=64): direct-load 64x64-per-wave, 3-term, softplus epilogue
__global__ __launch_bounds__(64)
void gemm_dt(const u16* __restrict__ Ah, const u16* __restrict__ Al, int lda,
             const u16* __restrict__ Bh, const u16* __restrict__ Bl, int ldb,
             float* __restrict__ C, int ldc, int K, const float* __restrict__ bias)
{
    const int lane = threadIdx.x;
    const int r16  = lane & 15;
    const int quad = lane >> 4;
    const long m0 = (long)blockIdx.y * 64;
    const long n0 = (long)blockIdx.x * 64;

    const u16* Ahp[4]; const u16* Alp[4];
    const u16* Bhp[4]; const u16* Blp[4];
    #pragma unroll
    for (int i = 0; i < 4; i++) {
        long ra = (m0 + r16 + 16 * i) * (long)lda + quad * 8;
        long rb = (n0 + r16 + 16 * i) * (long)ldb + quad * 8;
        Ahp[i] = Ah + ra; Alp[i] = Al + ra;
        Bhp[i] = Bh + rb; Blp[i] = Bl + rb;
    }

    f32x4 acc[4][4];
    #pragma unroll
    for (int i = 0; i < 4; i++)
        #pragma unroll
        for (int j = 0; j < 4; j++) acc[i][j] = {0.f, 0.f, 0.f, 0.f};

    for (int k = 0; k < K; k += 32) {
        bf16x8 ah[4], al[4], bh[4], bl[4];
        #pragma unroll
        for (int i = 0; i < 4; i++) {
            ah[i] = *(const bf16x8*)(Ahp[i] + k);
            al[i] = *(const bf16x8*)(Alp[i] + k);
            bh[i] = *(const bf16x8*)(Bhp[i] + k);
            bl[i] = *(const bf16x8*)(Blp[i] + k);
        }
        #pragma unroll
        for (int i = 0; i < 4; i++) {
            #pragma unroll
            for (int j = 0; j < 4; j++) {
                acc[i][j] = mfma16(ah[i], bh[j], acc[i][j]);
                acc[i][j] = mfma16(ah[i], bl[j], acc[i][j]);
                acc[i][j] = mfma16(al[i], bh[j], acc[i][j]);
            }
        }
    }

    #pragma unroll
    for (int i = 0; i < 4; i++) {
        #pragma unroll
        for (int j = 0; j < 4; j++) {
            long col = n0 + j * 16 + r16;
            #pragma unroll
            for (int r = 0; r < 4; r++) {
                long row = m0 + i * 16 + quad * 4 + r;
                float x = acc[i][j][r] + bias[col];
                x = (x > 15.f) ? x : log1pf(__expf(x));
                C[row * (long)ldc + col] = x;
            }
        }
    }
}

// GEMM3: xdbc += u @ W_xproj^T, split-K over blockIdx.z, 32x32 tile per wave
__global__ __launch_bounds__(64)
void gemm3_splitk(const u16* __restrict__ A, int lda,
                  const u16* __restrict__ Bh, const u16* __restrict__ Bl, int ldb,
                  float* __restrict__ C, int ldc, int K0)
{
    const int lane = threadIdx.x;
    const int r16  = lane & 15;
    const int quad = lane >> 4;
    const long m0 = (long)blockIdx.y * 32;
    const long n0 = (long)blockIdx.x * 32;
    const int kbase = blockIdx.z * K0;

    const u16* Ap0 = A  + (m0 + r16) * (long)lda + quad * 8 + kbase;
    const u16* Ap1 = Ap0 + 16L * lda;
    const u16* Bh0 = Bh + (n0 + r16) * (long)ldb + quad * 8 + kbase;
    const u16* Bh1 = Bh0 + 16L * ldb;
    const u16* Bl0 = Bl + (n0 + r16) * (long)ldb + quad * 8 + kbase;
    const u16* Bl1 = Bl0 + 16L * ldb;

    f32x4 acc00 = {0,0,0,0}, acc01 = {0,0,0,0}, acc10 = {0,0,0,0}, acc11 = {0,0,0,0};

    for (int k = 0; k < K0; k += 32) {
        bf16x8 a0 = *(const bf16x8*)(Ap0 + k);
        bf16x8 a1 = *(const bf16x8*)(Ap1 + k);
        bf16x8 b0h = *(const bf16x8*)(Bh0 + k);
        bf16x8 b1h = *(const bf16x8*)(Bh1 + k);
        bf16x8 b0l = *(const bf16x8*)(Bl0 + k);
        bf16x8 b1l = *(const bf16x8*)(Bl1 + k);
        acc00 = mfma16(a0, b0h, acc00); acc00 = mfma16(a0, b0l, acc00);
        acc01 = mfma16(a0, b1h, acc01); acc01 = mfma16(a0, b1l, acc01);
        acc10 = mfma16(a1, b0h, acc10); acc10 = mfma16(a1, b0l, acc10);
        acc11 = mfma16(a1, b1h, acc11); acc11 = mfma16(a1, b1l, acc11);
    }

    #pragma unroll
    for (int i = 0; i < 2; i++) {
        #pragma unroll
        for (int j = 0; j < 2; j++) {
            f32x4 v = (i == 0) ? (j == 0 ? acc00 : acc01) : (j == 0 ? acc10 : acc11);
            long col = n0 + j * 16 + r16;
            #pragma unroll
            for (int r = 0; r < 4; r++) {
                long row = m0 + i * 16 + quad * 4 + r;
                atomicAdd(&C[row * (long)ldc + col], v[r]);
            }
        }
    }
}

// depthwise causal conv(4) + bias + silu, 8 channels per thread
__global__ __launch_bounds__(256)
void conv_silu(const u16* __restrict__ xc, const float* __restrict__ cw,
               const float* __restrict__ cb, u16* __restrict__ u)
{
    long idx = ((long)blockIdx.x * 256 + threadIdx.x) * 8;  // row*2048 + d0
    int d0 = (int)(idx & 2047);
    int t  = (int)((idx >> 11) & 2047);

    bf16x8 xrow[4];
    #pragma unroll
    for (int j = 0; j < 4; j++) {
        int tt = t - 3 + j;
        if (tt >= 0) xrow[j] = *(const bf16x8*)(xc + idx + (long)(j - 3) * D_INNER);
        else         xrow[j] = bf16x8{0,0,0,0,0,0,0,0};
    }
    u16x8 out;
    #pragma unroll
    for (int e = 0; e < 8; e++) {
        int d = d0 + e;
        float acc = cb[d];
        #pragma unroll
        for (int j = 0; j < 4; j++)
            acc += cw[d * 4 + j] * (float)xrow[j][e];
        out[e] = f2bf(acc / (1.f + __expf(-acc)));
    }
    *(u16x8*)(u + idx) = out;
}

// ---- chunked parallel scan: pass A ----
__global__ __launch_bounds__(256)
void scan_partA(const float* __restrict__ delta, const u16* __restrict__ u,
                const float* __restrict__ xdbc, const float* __restrict__ A_log,
                float* __restrict__ hbuf, float* __restrict__ sdelta)
{
    const int d = blockIdx.x * 256 + threadIdx.x;
    const int c = blockIdx.y;
    const int b = blockIdx.z;
    const int t0 = c * CHUNK_T;

    float Af[16];
    #pragma unroll
    for (int s = 0; s < 16; s++) Af[s] = -__expf(A_log[d * 16 + s]) * LOG2E;

    float h[16];
    #pragma unroll
    for (int s = 0; s < 16; s++) h[s] = 0.f;
    float sd = 0.f;

    const float* dptr = delta + ((long)b * SEQ + t0) * D_INNER + d;
    const u16*   uptr = u     + ((long)b * SEQ + t0) * D_INNER + d;
    const float* xp   = xdbc  + ((long)b * SEQ + t0) * XPROJ_N;

    for (int t = 0; t < CHUNK_T; t++) {
        float dl = dptr[(long)t * D_INNER];
        float uu = bf2f(uptr[(long)t * D_INNER]);
        f32x4 B0 = *(const f32x4*)(xp + t * XPROJ_N + DT_RANK);
        f32x4 B1 = *(const f32x4*)(xp + t * XPROJ_N + DT_RANK + 4);
        f32x4 B2 = *(const f32x4*)(xp + t * XPROJ_N + DT_RANK + 8);
        f32x4 B3 = *(const f32x4*)(xp + t * XPROJ_N + DT_RANK + 12);
        float Bv[16] = {B0[0],B0[1],B0[2],B0[3], B1[0],B1[1],B1[2],B1[3],
                        B2[0],B2[1],B2[2],B2[3], B3[0],B3[1],B3[2],B3[3]};
        sd += dl;
        float dlu = dl * uu;
        #pragma unroll
        for (int s = 0; s < 16; s++)
            h[s] = h[s] * exp2f(dl * Af[s]) + dlu * Bv[s];
    }

    float* hout = hbuf + ((long)(b * NCHUNK + c) * D_INNER + d) * 16;
    #pragma unroll
    for (int s = 0; s < 16; s++) hout[s] = h[s];
    sdelta[(long)(b * NCHUNK + c) * D_INNER + d] = sd;
}

// ---- pass B: compose chunk boundaries (in-place: hbuf h_end -> h_in) ----
__global__ __launch_bounds__(256)
void scan_fixup(float* __restrict__ hbuf, const float* __restrict__ sdelta,
                const float* __restrict__ A_log)
{
    const int idx = blockIdx.x * 256 + threadIdx.x;
    const int ds = idx & (D_INNER * 16 - 1);
    const int b  = idx >> 15;
    const float Af = -__expf(A_log[ds]) * LOG2E;
    float hin = 0.f;
    #pragma unroll 4
    for (int c = 0; c < NCHUNK; c++) {
        long gi = (long)(b * NCHUNK + c) * (D_INNER * 16) + ds;
        float e = hbuf[gi];
        hbuf[gi] = hin;
        float sd = sdelta[(long)(b * NCHUNK + c) * D_INNER + (ds >> 4)];
        hin = e + exp2f(Af * sd) * hin;
    }
}

// ---- pass C: full scan from h_in, fused +u*D and *silu(z), write y (bf16) ----
__global__ __launch_bounds__(256)
void scan_partC(const float* __restrict__ delta, const u16* __restrict__ u,
                const float* __restrict__ xdbc, const float* __restrict__ z,
                const float* __restrict__ A_log, const float* __restrict__ Dp,
                const float* __restrict__ hbuf, u16* __restrict__ y)
{
    const int d = blockIdx.x * 256 + threadIdx.x;
    const int c = blockIdx.y;
    const int b = blockIdx.z;
    const int t0 = c * CHUNK_T;

    float Af[16];
    #pragma unroll
    for (int s = 0; s < 16; s++) Af[s] = -__expf(A_log[d * 16 + s]) * LOG2E;
    const float Dd = Dp[d];

    float h[16];
    const float* hin = hbuf + ((long)(b * NCHUNK + c) * D_INNER + d) * 16;
    #pragma unroll
    for (int s = 0; s < 16; s++) h[s] = hin[s];

    const float* dptr = delta + ((long)b * SEQ + t0) * D_INNER + d;
    const u16*   uptr = u     + ((long)b * SEQ + t0) * D_INNER + d;
    const float* zptr = z     + ((long)b * SEQ + t0) * D_INNER + d;
    const float* xp   = xdbc  + ((long)b * SEQ + t0) * XPROJ_N;
    u16* yptr = y + ((long)b * SEQ + t0) * D_INNER + d;

    for (int t = 0; t < CHUNK_T; t++) {
        float dl = dptr[(long)t * D_INNER];
        float uu = bf2f(uptr[(long)t * D_INNER]);
        float zl = zptr[(long)t * D_INNER];
        f32x4 B0 = *(const f32x4*)(xp + t * XPROJ_N + DT_RANK);
        f32x4 B1 = *(const f32x4*)(xp + t * XPROJ_N + DT_RANK + 4);
        f32x4 B2 = *(const f32x4*)(xp + t * XPROJ_N + DT_RANK + 8);
        f32x4 B3 = *(const f32x4*)(xp + t * XPROJ_N + DT_RANK + 12);
        f32x4 C0 = *(const f32x4*)(xp + t * XPROJ_N + DT_RANK + 16);
        f32x4 C1 = *(const f32x4*)(xp + t * XPROJ_N + DT_RANK + 20);
        f32x4 C2 = *(const f32x4*)(xp + t * XPROJ_N + DT_RANK + 24);
        f32x4 C3 = *(const f32x4*)(xp + t * XPROJ_N + DT_RANK + 28);
        float Bv[16] = {B0[0],B0[1],B0[2],B0[3], B1[0],B1[1],B1[2],B1[3],
                        B2[0],B2[1],B2[2],B2[3], B3[0],B3[1],B3[2],B3[3]};
        float Cv[16] = {C0[0],C0[1],C0[2],C0[3], C1[0],C1[1],C1[2],C1[3],
                        C2[0],C2[1],C2[2],C2[3], C3[0],C3[1],C3[2],C3[3]};
        float dlu = dl * uu;
        float p0 = 0.f, p1 = 0.f, p2 = 0.f, p3 = 0.f;
        #pragma unroll
        for (int s = 0; s < 16; s += 4) {
            h[s]   = h[s]   * exp2f(dl * Af[s])   + dlu * Bv[s];
            h[s+1] = h[s+1] * exp2f(dl * Af[s+1]) + dlu * Bv[s+1];
            h[s+2] = h[s+2] * exp2f(dl * Af[s+2]) + dlu * Bv[s+2];
            h[s+3] = h[s+3] * exp2f(dl * Af[s+3]) + dlu * Bv[s+3];
            p0 += h[s]   * Cv[s];
            p1 += h[s+1] * Cv[s+1];
            p2 += h[s+2] * Cv[s+2];
            p3 += h[s+3] * Cv[s+3];
        }
        float acc = (p0 + p1) + (p2 + p3);
        float sz = zl / (1.f + __expf(-zl));
        float yy = (acc + uu * Dd) * sz;
        yptr[(long)t * D_INNER] = f2bf(yy);
    }
}

// layernorm over sum of 4 split-K partials
__global__ __launch_bounds__(256)
void layernorm_kernel(const float* __restrict__ pa, const float* __restrict__ pb,
                      const float* __restrict__ pc, const float* __restrict__ pd,
                      const float* __restrict__ gamma, const float* __restrict__ beta,
                      float* __restrict__ out)
{
    const long row = blockIdx.x;
    const long base = row * DIM;
    int tid = threadIdx.x;
    float v[4];
    float sum = 0.f, sq = 0.f;
    #pragma unroll
    for (int i = 0; i < 4; i++) {
        long c = base + tid + i * 256;
        v[i] = (pa[c] + pb[c]) + (pc[c] + pd[c]);
        sum += v[i];
        sq  += v[i] * v[i];
    }
    #pragma unroll
    for (int off = 1; off < 64; off <<= 1) {
        sum += __shfl_xor(sum, off);
        sq  += __shfl_xor(sq, off);
    }
    __shared__ float ssum[4], ssq[4];
    int w = tid >> 6;
    if ((tid & 63) == 0) { ssum[w] = sum; ssq[w] = sq; }
    __syncthreads();
    float ts = ssum[0] + ssum[1] + ssum[2] + ssum[3];
    float tq = ssq[0] + ssq[1] + ssq[2] + ssq[3];
    float mean = ts * (1.f / DIM);
    float var  = tq * (1.f / DIM) - mean * mean;
    float rstd = rsqrtf(var + 1e-5f);
    float* o = out + base;
    #pragma unroll
    for (int i = 0; i < 4; i++) {
        int c = tid + i * 256;
        o[c] = (v[i] - mean) * rstd * gamma[c] + beta[c];
    }
}

extern "C" void kernel_launch(void* const* d_in, const int* in_sizes, int n_in,
                              void* d_out, int out_size, void* d_ws, size_t ws_size,
                              hipStream_t stream)
{
    const float* x      = (const float*)d_in[0];
    const float* W_in   = (const float*)d_in[1];
    const float* conv_w = (const float*)d_in[2];
    const float* conv_b = (const float*)d_in[3];
    const float* W_xproj= (const float*)d_in[4];
    const float* W_dt   = (const float*)d_in[5];
    const float* b_dt   = (const float*)d_in[6];
    const float* A_log  = (const float*)d_in[7];
    const float* Dv     = (const float*)d_in[8];
    const float* W_out  = (const float*)d_in[9];
    const float* gamma  = (const float*)d_in[10];
    const float* beta   = (const float*)d_in[11];

    char* ws = (char*)d_ws;
    // [0,16M): xc; later xdh/xdl + wx/wdt splits; later hbuf/sdel
    u16*   xc    = (u16*)(ws);
    u16*   xdh   = (u16*)(ws);
    u16*   xdl   = (u16*)(ws + 786432);
    u16*   wxh   = (u16*)(ws + 1572864);
    u16*   wxl   = (u16*)(ws + 1966080);
    u16*   wdth  = (u16*)(ws + 2359296);
    u16*   wdtl  = (u16*)(ws + 2621440);
    float* hbuf  = (float*)(ws);
    float* sdel  = (float*)(ws + 8388608);
    // [16M,48M): z; later opre partials 0,1
    float* z     = (float*)(ws + 16777216);
    float* opreA = (float*)(ws + 16777216);      // partials kz=0,1 (2 x 16MB)
    // [48M,64M): u; later W_out splits
    u16*   u     = (u16*)(ws + 50331648);
    u16*   wouth = (u16*)(ws + 50331648);
    u16*   woutl = (u16*)(ws + 54525952);
    // [64M,96M): GEMM1 splits; later delta; later opre partials 2,3
    u16*   xh    = (u16*)(ws + 67108864);
    u16*   xl    = (u16*)(ws + 75497472);
    u16*   wh    = (u16*)(ws + 83886080);
    u16*   wl    = (u16*)(ws + 92274688);
    float* delta = (float*)(ws + 67108864);
    float* opreB = (float*)(ws + 67108864);      // partials kz=2,3 (2 x 16MB)
    // [96M,97.5M): xdbc f32
    float* xdbc  = (float*)(ws + 100663296);
    u16*   yb    = (u16*)d_out;

    // 0) pre-split GEMM1 operands (x + W_in fused into one launch)
    split2_kernel<<<32768, 256, 0, stream>>>(x, xh, xl, 4194304,
                                             W_in, wh, wl, 4194304);
    // 1) xz = x @ W_in^T -> xc bf16 | z f32   (M=4096,N=4096,K=1024)
    gemm128<3, EPI_XZ><<<dim3(32, 32), 256, 0, stream>>>(
        xh, xl, DIM, wh, wl, DIM, xc, z, 0, DIM, nullptr);
    // 2) u = silu(conv4(xc)+cb)
    conv_silu<<<4096, 256, 0, stream>>>(xc, conv_w, conv_b, u);
    // 2b) small weight splits (W_xproj + W_dt fused)
    split2_kernel<<<1280, 256, 0, stream>>>(W_xproj, wxh, wxl, 196608,
                                            W_dt, wdth, wdtl, 131072);
    // 3) xdbc = u @ W_xproj^T  (split-K=8, atomic f32)
    zero_kernel<<<1536, 256, 0, stream>>>(xdbc, 393216);
    gemm3_splitk<<<dim3(3, 128, 8), 64, 0, stream>>>(
        u, D_INNER, wxh, wxl, D_INNER, xdbc, XPROJ_N, 256);
    // 3b) split xdbc for GEMM2's A operand
    split_kernel<<<1536, 256, 0, stream>>>(xdbc, xdh, xdl, 393216);
    // 4) delta = softplus(dt @ W_dt^T + b_dt)  (M=4096,N=2048,K=64)
    gemm_dt<<<dim3(32, 64), 64, 0, stream>>>(
        xdh, xdl, XPROJ_N, wdth, wdtl, DT_RANK, delta, D_INNER, DT_RANK, b_dt);
    // 5) chunked parallel scan
    scan_partA<<<dim3(8, NCHUNK, BSZ), 256, 0, stream>>>(delta, u, xdbc, A_log, hbuf, sdel);
    scan_fixup<<<256, 256, 0, stream>>>(hbuf, sdel, A_log);
    scan_partC<<<dim3(8, NCHUNK, BSZ), 256, 0, stream>>>(delta, u, xdbc, z, A_log, Dv, hbuf, yb);
    // 5b) split W_out (into dead u region)
    split_kernel<<<8192, 256, 0, stream>>>(W_out, wouth, woutl, 2097152);
    // 6) opre[kz] = yb @ W_out^T slice  (split-K=4, 4 partial f32 buffers)
    gemm128_sk2<<<dim3(8, 32, 4), 256, 0, stream>>>(
        yb, D_INNER, wouth, woutl, D_INNER, opreA, opreB, DIM, 512);
    // 7) layernorm over sum of partials -> d_out f32
    layernorm_kernel<<<4096, 256, 0, stream>>>(
        opreA, opreA + 4194304, opreB, opreB + 4194304, gamma, beta, (float*)d_out);
}

// Round 8
// 461.446 us; speedup vs baseline: 3.3279x; 1.0456x over previous
//
#include <hip/hip_runtime.h>
#include <stdint.h>

typedef unsigned short u16;
typedef __bf16 bf16x8 __attribute__((ext_vector_type(8)));
typedef unsigned short u16x8 __attribute__((ext_vector_type(8)));
typedef float f32x4 __attribute__((ext_vector_type(4)));

#define BSZ 2
#define SEQ 2048
#define DIM 1024
#define D_INNER 2048
#define DT_RANK 64
#define D_STATE 16
#define XPROJ_N 96   // DT_RANK + 2*D_STATE
#define NCHUNK 32
#define CHUNK_T 64   // SEQ / NCHUNK
#define LOG2E 1.44269504f

#define N_X   4194304   // x: 2*2048*1024
#define N_W   4194304   // W_in: 4096*1024
#define N_WX  196608    // W_xproj: 96*2048
#define N_WDT 131072    // W_dt: 2048*64
#define N_WO  2097152   // W_out: 1024*2048
#define N_XD  393216    // xdbc: 4096*96

__device__ __forceinline__ float bf2f(u16 h) {
    return __uint_as_float(((unsigned)h) << 16);
}
__device__ __forceinline__ u16 f2bf(float f) {
    unsigned u = __float_as_uint(f);
    unsigned r = (u + 0x7FFFu + ((u >> 16) & 1u)) >> 16;
    return (u16)r;
}

__device__ __forceinline__ f32x4 mfma16(bf16x8 a, bf16x8 b, f32x4 c) {
    return __builtin_amdgcn_mfma_f32_16x16x32_bf16(a, b, c, 0, 0, 0);
}

__device__ __forceinline__ void gload_lds16(const void* g, void* l) {
    __builtin_amdgcn_global_load_lds(
        (const __attribute__((address_space(1))) unsigned int*)(uintptr_t)g,
        (__attribute__((address_space(3))) unsigned int*)(uintptr_t)l,
        16, 0, 0);
}

__device__ __forceinline__ void split1(const float* in, u16* hi, u16* lo, int i) {
    float v = in[i];
    u16 h = f2bf(v);
    hi[i] = h;
    lo[i] = f2bf(v - bf2f(h));
}

// split x, W_in, W_xproj, W_dt -> bf16 hi/lo, one launch
__global__ __launch_bounds__(256)
void megasplit4(const float* __restrict__ x,  u16* __restrict__ xh,  u16* __restrict__ xl,
                const float* __restrict__ w,  u16* __restrict__ wh,  u16* __restrict__ wl,
                const float* __restrict__ wx, u16* __restrict__ wxh, u16* __restrict__ wxl,
                const float* __restrict__ wd, u16* __restrict__ wdh, u16* __restrict__ wdl)
{
    int i = blockIdx.x * 256 + threadIdx.x;
    if (i < N_X) { split1(x, xh, xl, i); return; }
    i -= N_X;
    if (i < N_W) { split1(w, wh, wl, i); return; }
    i -= N_W;
    if (i < N_WX) { split1(wx, wxh, wxl, i); return; }
    i -= N_WX;
    if (i < N_WDT) { split1(wd, wdh, wdl, i); }
}

__global__ __launch_bounds__(256)
void split_kernel(const float* __restrict__ in, u16* __restrict__ hi,
                  u16* __restrict__ lo, int n)
{
    int i = blockIdx.x * 256 + threadIdx.x;
    if (i < n) split1(in, hi, lo, i);
}

enum { EPI_XZ = 0, EPI_F32 = 1, EPI_SOFTPLUS = 2 };

// 128x128 tile per 256-thread block, BK=32, global_load_lds staging, swizzled
// LDS. TERMS=3: ah*bh+ah*bl+al*bh. TERMS=2: a*bh+a*bl.
template<int TERMS, int EPI>
__global__ __launch_bounds__(256)
void gemm128(const u16* __restrict__ Ah, const u16* __restrict__ Al, int lda,
             const u16* __restrict__ Bh, const u16* __restrict__ Bl, int ldb,
             void* __restrict__ C, void* __restrict__ C2, int ldc,
             int K, const float* __restrict__ bias)
{
    __shared__ u16 lds[(TERMS == 3) ? 16384 : 12288];
    u16* Ah_l = lds;
    u16* Al_l = lds + 4096;
    u16* Bh_l = lds + ((TERMS == 3) ? 8192 : 4096);
    u16* Bl_l = lds + ((TERMS == 3) ? 12288 : 8192);

    const int tid  = threadIdx.x;
    const int w    = tid >> 6;
    const int lane = tid & 63;
    const int r16  = lane & 15;
    const int quad = lane >> 4;
    const int wr   = w >> 1;
    const int wc   = w & 1;
    const long m0  = (long)blockIdx.y * 128;
    const long n0  = (long)blockIdx.x * 128;

    const int c0 = w * 64 + lane;
    const int c1 = 256 + c0;
    const int ma0 = c0 >> 2, kca0 = ((c0 & 3) ^ ((ma0 >> 1) & 3)) * 8;
    const int ma1 = c1 >> 2, kca1 = ((c1 & 3) ^ ((ma1 >> 1) & 3)) * 8;

    const u16* Arow0 = Ah + (m0 + ma0) * (long)lda + kca0;
    const u16* Arow1 = Ah + (m0 + ma1) * (long)lda + kca1;
    const u16* Alrow0 = (TERMS == 3) ? Al + (m0 + ma0) * (long)lda + kca0 : nullptr;
    const u16* Alrow1 = (TERMS == 3) ? Al + (m0 + ma1) * (long)lda + kca1 : nullptr;
    const u16* Brow0 = Bh + (n0 + ma0) * (long)ldb + kca0;
    const u16* Brow1 = Bh + (n0 + ma1) * (long)ldb + kca1;
    const u16* Blrow0 = Bl + (n0 + ma0) * (long)ldb + kca0;
    const u16* Blrow1 = Bl + (n0 + ma1) * (long)ldb + kca1;

    f32x4 acc[4][4];
    #pragma unroll
    for (int i = 0; i < 4; i++)
        #pragma unroll
        for (int j = 0; j < 4; j++) acc[i][j] = {0.f, 0.f, 0.f, 0.f};

    int caof[4], cbof[4];
    #pragma unroll
    for (int i = 0; i < 4; i++) {
        int m = wr * 64 + i * 16 + r16;
        caof[i] = (m * 4 + (quad ^ ((m >> 1) & 3))) * 8;
        int n = wc * 64 + i * 16 + r16;
        cbof[i] = (n * 4 + (quad ^ ((n >> 1) & 3))) * 8;
    }

    for (int k0 = 0; k0 < K; k0 += 32) {
        __syncthreads();
        gload_lds16(Arow0 + k0, Ah_l + c0 * 8);
        gload_lds16(Arow1 + k0, Ah_l + c1 * 8);
        if (TERMS == 3) {
            gload_lds16(Alrow0 + k0, Al_l + c0 * 8);
            gload_lds16(Alrow1 + k0, Al_l + c1 * 8);
        }
        gload_lds16(Brow0 + k0, Bh_l + c0 * 8);
        gload_lds16(Brow1 + k0, Bh_l + c1 * 8);
        gload_lds16(Blrow0 + k0, Bl_l + c0 * 8);
        gload_lds16(Blrow1 + k0, Bl_l + c1 * 8);
        __syncthreads();

        bf16x8 fah[4], fal[4], fbh[4], fbl[4];
        #pragma unroll
        for (int i = 0; i < 4; i++) {
            fah[i] = *(const bf16x8*)(Ah_l + caof[i]);
            if (TERMS == 3) fal[i] = *(const bf16x8*)(Al_l + caof[i]);
            fbh[i] = *(const bf16x8*)(Bh_l + cbof[i]);
            fbl[i] = *(const bf16x8*)(Bl_l + cbof[i]);
        }
        #pragma unroll
        for (int i = 0; i < 4; i++) {
            #pragma unroll
            for (int j = 0; j < 4; j++) {
                acc[i][j] = mfma16(fah[i], fbh[j], acc[i][j]);
                acc[i][j] = mfma16(fah[i], fbl[j], acc[i][j]);
                if (TERMS == 3) acc[i][j] = mfma16(fal[i], fbh[j], acc[i][j]);
            }
        }
    }

    #pragma unroll
    for (int i = 0; i < 4; i++) {
        #pragma unroll
        for (int j = 0; j < 4; j++) {
            long col = n0 + wc * 64 + j * 16 + r16;
            #pragma unroll
            for (int r = 0; r < 4; r++) {
                long row = m0 + wr * 64 + i * 16 + quad * 4 + r;
                float x = acc[i][j][r];
                if (EPI == EPI_XZ) {
                    if (col < D_INNER) ((u16*)C)[row * (long)D_INNER + col] = f2bf(x);
                    else ((float*)C2)[row * (long)D_INNER + (col - D_INNER)] = x;
                } else if (EPI == EPI_SOFTPLUS) {
                    x += bias[col];
                    x = (x > 15.f) ? x : log1pf(__expf(x));
                    ((float*)C)[row * (long)ldc + col] = x;
                } else {
                    ((float*)C)[row * (long)ldc + col] = x;
                }
            }
        }
    }
}

// GEMM4 split-K=2: 128x128 tile, TERMS=2, kz slice -> own f32 partial buffer
__global__ __launch_bounds__(256)
void gemm128_sk2(const u16* __restrict__ Ah, int lda,
                 const u16* __restrict__ Bh, const u16* __restrict__ Bl, int ldb,
                 float* __restrict__ OutBase, int ldc, int K0)
{
    __shared__ u16 lds[12288];
    u16* Ah_l = lds;
    u16* Bh_l = lds + 4096;
    u16* Bl_l = lds + 8192;

    const int tid  = threadIdx.x;
    const int w    = tid >> 6;
    const int lane = tid & 63;
    const int r16  = lane & 15;
    const int quad = lane >> 4;
    const int wr   = w >> 1;
    const int wc   = w & 1;
    const long m0  = (long)blockIdx.y * 128;
    const long n0  = (long)blockIdx.x * 128;
    const int kbase = blockIdx.z * K0;
    float* Out = OutBase + (long)blockIdx.z * 4194304;

    const int c0 = w * 64 + lane;
    const int c1 = 256 + c0;
    const int ma0 = c0 >> 2, kca0 = ((c0 & 3) ^ ((ma0 >> 1) & 3)) * 8;
    const int ma1 = c1 >> 2, kca1 = ((c1 & 3) ^ ((ma1 >> 1) & 3)) * 8;

    const u16* Arow0 = Ah + (m0 + ma0) * (long)lda + kbase + kca0;
    const u16* Arow1 = Ah + (m0 + ma1) * (long)lda + kbase + kca1;
    const u16* Brow0 = Bh + (n0 + ma0) * (long)ldb + kbase + kca0;
    const u16* Brow1 = Bh + (n0 + ma1) * (long)ldb + kbase + kca1;
    const u16* Blrow0 = Bl + (n0 + ma0) * (long)ldb + kbase + kca0;
    const u16* Blrow1 = Bl + (n0 + ma1) * (long)ldb + kbase + kca1;

    f32x4 acc[4][4];
    #pragma unroll
    for (int i = 0; i < 4; i++)
        #pragma unroll
        for (int j = 0; j < 4; j++) acc[i][j] = {0.f, 0.f, 0.f, 0.f};

    int caof[4], cbof[4];
    #pragma unroll
    for (int i = 0; i < 4; i++) {
        int m = wr * 64 + i * 16 + r16;
        caof[i] = (m * 4 + (quad ^ ((m >> 1) & 3))) * 8;
        int n = wc * 64 + i * 16 + r16;
        cbof[i] = (n * 4 + (quad ^ ((n >> 1) & 3))) * 8;
    }

    for (int k0 = 0; k0 < K0; k0 += 32) {
        __syncthreads();
        gload_lds16(Arow0 + k0, Ah_l + c0 * 8);
        gload_lds16(Arow1 + k0, Ah_l + c1 * 8);
        gload_lds16(Brow0 + k0, Bh_l + c0 * 8);
        gload_lds16(Brow1 + k0, Bh_l + c1 * 8);
        gload_lds16(Blrow0 + k0, Bl_l + c0 * 8);
        gload_lds16(Blrow1 + k0, Bl_l + c1 * 8);
        __syncthreads();

        bf16x8 fah[4], fbh[4], fbl[4];
        #pragma unroll
        for (int i = 0; i < 4; i++) {
            fah[i] = *(const bf16x8*)(Ah_l + caof[i]);
            fbh[i] = *(const bf16x8*)(Bh_l + cbof[i]);
            fbl[i] = *(const bf16x8*)(Bl_l + cbof[i]);
        }
        #pragma unroll
        for (int i = 0; i < 4; i++) {
            #pragma unroll
            for (int j = 0; j < 4; j++) {
                acc[i][j] = mfma16(fah[i], fbh[j], acc[i][j]);
                acc[i][j] = mfma16(fah[i], fbl[j], acc[i][j]);
            }
        }
    }

    #pragma unroll
    for (int i = 0; i < 4; i++) {
        #pragma unroll
        for (int j = 0; j < 4; j++) {
            long col = n0 + wc * 64 + j * 16 + r16;
            #pragma unroll
            for (int r = 0; r < 4; r++) {
                long row = m0 + wr * 64 + i * 16 + quad * 4 + r;
                Out[row * (long)ldc + col] = acc[i][j][r];
            }
        }
    }
}

// GEMM2 (K=64): 32x32 per wave, 3-term, softplus epilogue, 8192 waves
__global__ __launch_bounds__(64)
void gemm_dt32(const u16* __restrict__ Ah, const u16* __restrict__ Al, int lda,
               const u16* __restrict__ Bh, const u16* __restrict__ Bl, int ldb,
               float* __restrict__ C, int ldc, const float* __restrict__ bias)
{
    const int lane = threadIdx.x;
    const int r16  = lane & 15;
    const int quad = lane >> 4;
    const long m0 = (long)blockIdx.y * 32;
    const long n0 = (long)blockIdx.x * 32;

    const u16* Ah0 = Ah + (m0 + r16) * (long)lda + quad * 8;
    const u16* Ah1 = Ah0 + 16L * lda;
    const u16* Al0 = Al + (m0 + r16) * (long)lda + quad * 8;
    const u16* Al1 = Al0 + 16L * lda;
    const u16* Bh0 = Bh + (n0 + r16) * (long)ldb + quad * 8;
    const u16* Bh1 = Bh0 + 16L * ldb;
    const u16* Bl0 = Bl + (n0 + r16) * (long)ldb + quad * 8;
    const u16* Bl1 = Bl0 + 16L * ldb;

    f32x4 acc00 = {0,0,0,0}, acc01 = {0,0,0,0}, acc10 = {0,0,0,0}, acc11 = {0,0,0,0};

    #pragma unroll
    for (int k = 0; k < DT_RANK; k += 32) {
        bf16x8 a0h = *(const bf16x8*)(Ah0 + k);
        bf16x8 a1h = *(const bf16x8*)(Ah1 + k);
        bf16x8 a0l = *(const bf16x8*)(Al0 + k);
        bf16x8 a1l = *(const bf16x8*)(Al1 + k);
        bf16x8 b0h = *(const bf16x8*)(Bh0 + k);
        bf16x8 b1h = *(const bf16x8*)(Bh1 + k);
        bf16x8 b0l = *(const bf16x8*)(Bl0 + k);
        bf16x8 b1l = *(const bf16x8*)(Bl1 + k);
        acc00 = mfma16(a0h, b0h, acc00); acc00 = mfma16(a0h, b0l, acc00); acc00 = mfma16(a0l, b0h, acc00);
        acc01 = mfma16(a0h, b1h, acc01); acc01 = mfma16(a0h, b1l, acc01); acc01 = mfma16(a0l, b1h, acc01);
        acc10 = mfma16(a1h, b0h, acc10); acc10 = mfma16(a1h, b0l, acc10); acc10 = mfma16(a1l, b0h, acc10);
        acc11 = mfma16(a1h, b1h, acc11); acc11 = mfma16(a1h, b1l, acc11); acc11 = mfma16(a1l, b1h, acc11);
    }

    #pragma unroll
    for (int i = 0; i < 2; i++) {
        #pragma unroll
        for (int j = 0; j < 2; j++) {
            f32x4 v = (i == 0) ? (j == 0 ? acc00 : acc01) : (j == 0 ? acc10 : acc11);
            long col = n0 + j * 16 + r16;
            #pragma unroll
            for (int r = 0; r < 4; r++) {
                long row = m0 + i * 16 + quad * 4 + r;
                float x = v[r] + bias[col];
                x = (x > 15.f) ? x : log1pf(__expf(x));
                C[row * (long)ldc + col] = x;
            }
        }
    }
}

// GEMM3: partial[kz] = u @ W_xproj^T over K-slice kz (no atomics)
__global__ __launch_bounds__(64)
void gemm3_skp(const u16* __restrict__ A, int lda,
               const u16* __restrict__ Bh, const u16* __restrict__ Bl, int ldb,
               float* __restrict__ Cpart, int ldc, int K0)
{
    const int lane = threadIdx.x;
    const int r16  = lane & 15;
    const int quad = lane >> 4;
    const long m0 = (long)blockIdx.y * 32;
    const long n0 = (long)blockIdx.x * 32;
    const int kbase = blockIdx.z * K0;
    float* C = Cpart + (long)blockIdx.z * N_XD;

    const u16* Ap0 = A  + (m0 + r16) * (long)lda + quad * 8 + kbase;
    const u16* Ap1 = Ap0 + 16L * lda;
    const u16* Bh0 = Bh + (n0 + r16) * (long)ldb + quad * 8 + kbase;
    const u16* Bh1 = Bh0 + 16L * ldb;
    const u16* Bl0 = Bl + (n0 + r16) * (long)ldb + quad * 8 + kbase;
    const u16* Bl1 = Bl0 + 16L * ldb;

    f32x4 acc00 = {0,0,0,0}, acc01 = {0,0,0,0}, acc10 = {0,0,0,0}, acc11 = {0,0,0,0};

    for (int k = 0; k < K0; k += 32) {
        bf16x8 a0 = *(const bf16x8*)(Ap0 + k);
        bf16x8 a1 = *(const bf16x8*)(Ap1 + k);
        bf16x8 b0h = *(const bf16x8*)(Bh0 + k);
        bf16x8 b1h = *(const bf16x8*)(Bh1 + k);
        bf16x8 b0l = *(const bf16x8*)(Bl0 + k);
        bf16x8 b1l = *(const bf16x8*)(Bl1 + k);
        acc00 = mfma16(a0, b0h, acc00); acc00 = mfma16(a0, b0l, acc00);
        acc01 = mfma16(a0, b1h, acc01); acc01 = mfma16(a0, b1l, acc01);
        acc10 = mfma16(a1, b0h, acc10); acc10 = mfma16(a1, b0l, acc10);
        acc11 = mfma16(a1, b1h, acc11); acc11 = mfma16(a1, b1l, acc11);
    }

    #pragma unroll
    for (int i = 0; i < 2; i++) {
        #pragma unroll
        for (int j = 0; j < 2; j++) {
            f32x4 v = (i == 0) ? (j == 0 ? acc00 : acc01) : (j == 0 ? acc10 : acc11);
            long col = n0 + j * 16 + r16;
            #pragma unroll
            for (int r = 0; r < 4; r++) {
                long row = m0 + i * 16 + quad * 4 + r;
                C[row * (long)ldc + col] = v[r];
            }
        }
    }
}

// combine 8 gemm3 partials -> xdbc f32 + hi/lo split
__global__ __launch_bounds__(256)
void combine3(const float* __restrict__ part, float* __restrict__ xdbc,
              u16* __restrict__ hi, u16* __restrict__ lo)
{
    int i = blockIdx.x * 256 + threadIdx.x;
    if (i >= N_XD) return;
    float s = 0.f;
    #pragma unroll
    for (int j = 0; j < 8; j++) s += part[(long)j * N_XD + i];
    xdbc[i] = s;
    u16 h = f2bf(s);
    hi[i] = h;
    lo[i] = f2bf(s - bf2f(h));
}

// depthwise causal conv(4) + bias + silu, 8 channels per thread
__global__ __launch_bounds__(256)
void conv_silu(const u16* __restrict__ xc, const float* __restrict__ cw,
               const float* __restrict__ cb, u16* __restrict__ u)
{
    long idx = ((long)blockIdx.x * 256 + threadIdx.x) * 8;
    int t  = (int)((idx >> 11) & 2047);
    int d0 = (int)(idx & 2047);

    bf16x8 xrow[4];
    #pragma unroll
    for (int j = 0; j < 4; j++) {
        int tt = t - 3 + j;
        if (tt >= 0) xrow[j] = *(const bf16x8*)(xc + idx + (long)(j - 3) * D_INNER);
        else         xrow[j] = bf16x8{0,0,0,0,0,0,0,0};
    }
    u16x8 out;
    #pragma unroll
    for (int e = 0; e < 8; e++) {
        int d = d0 + e;
        float acc = cb[d];
        #pragma unroll
        for (int j = 0; j < 4; j++)
            acc += cw[d * 4 + j] * (float)xrow[j][e];
        out[e] = f2bf(acc / (1.f + __expf(-acc)));
    }
    *(u16x8*)(u + idx) = out;
}

// ---- chunked parallel scan: pass A ----
__global__ __launch_bounds__(256)
void scan_partA(const float* __restrict__ delta, const u16* __restrict__ u,
                const float* __restrict__ xdbc, const float* __restrict__ A_log,
                float* __restrict__ hbuf, float* __restrict__ sdelta)
{
    const int d = blockIdx.x * 256 + threadIdx.x;
    const int c = blockIdx.y;
    const int b = blockIdx.z;
    const int t0 = c * CHUNK_T;

    float Af[16];
    #pragma unroll
    for (int s = 0; s < 16; s++) Af[s] = -__expf(A_log[d * 16 + s]) * LOG2E;

    float h[16];
    #pragma unroll
    for (int s = 0; s < 16; s++) h[s] = 0.f;
    float sd = 0.f;

    const float* dptr = delta + ((long)b * SEQ + t0) * D_INNER + d;
    const u16*   uptr = u     + ((long)b * SEQ + t0) * D_INNER + d;
    const float* xp   = xdbc  + ((long)b * SEQ + t0) * XPROJ_N;

    for (int t = 0; t < CHUNK_T; t++) {
        float dl = dptr[(long)t * D_INNER];
        float uu = bf2f(uptr[(long)t * D_INNER]);
        f32x4 B0 = *(const f32x4*)(xp + t * XPROJ_N + DT_RANK);
        f32x4 B1 = *(const f32x4*)(xp + t * XPROJ_N + DT_RANK + 4);
        f32x4 B2 = *(const f32x4*)(xp + t * XPROJ_N + DT_RANK + 8);
        f32x4 B3 = *(const f32x4*)(xp + t * XPROJ_N + DT_RANK + 12);
        float Bv[16] = {B0[0],B0[1],B0[2],B0[3], B1[0],B1[1],B1[2],B1[3],
                        B2[0],B2[1],B2[2],B2[3], B3[0],B3[1],B3[2],B3[3]};
        sd += dl;
        float dlu = dl * uu;
        #pragma unroll
        for (int s = 0; s < 16; s++)
            h[s] = h[s] * exp2f(dl * Af[s]) + dlu * Bv[s];
    }

    float* hout = hbuf + ((long)(b * NCHUNK + c) * D_INNER + d) * 16;
    #pragma unroll
    for (int s = 0; s < 16; s++) hout[s] = h[s];
    sdelta[(long)(b * NCHUNK + c) * D_INNER + d] = sd;
}

// ---- pass B: compose chunk boundaries (in-place: hbuf h_end -> h_in) ----
__global__ __launch_bounds__(256)
void scan_fixup(float* __restrict__ hbuf, const float* __restrict__ sdelta,
                const float* __restrict__ A_log)
{
    const int idx = blockIdx.x * 256 + threadIdx.x;
    const int ds = idx & (D_INNER * 16 - 1);
    const int b  = idx >> 15;
    const float Af = -__expf(A_log[ds]) * LOG2E;
    float hin = 0.f;
    #pragma unroll 4
    for (int c = 0; c < NCHUNK; c++) {
        long gi = (long)(b * NCHUNK + c) * (D_INNER * 16) + ds;
        float e = hbuf[gi];
        hbuf[gi] = hin;
        float sd = sdelta[(long)(b * NCHUNK + c) * D_INNER + (ds >> 4)];
        hin = e + exp2f(Af * sd) * hin;
    }
}

// ---- pass C: full scan from h_in, fused +u*D and *silu(z), write y (bf16) ----
__global__ __launch_bounds__(256)
void scan_partC(const float* __restrict__ delta, const u16* __restrict__ u,
                const float* __restrict__ xdbc, const float* __restrict__ z,
                const float* __restrict__ A_log, const float* __restrict__ Dp,
                const float* __restrict__ hbuf, u16* __restrict__ y)
{
    const int d = blockIdx.x * 256 + threadIdx.x;
    const int c = blockIdx.y;
    const int b = blockIdx.z;
    const int t0 = c * CHUNK_T;

    float Af[16];
    #pragma unroll
    for (int s = 0; s < 16; s++) Af[s] = -__expf(A_log[d * 16 + s]) * LOG2E;
    const float Dd = Dp[d];

    float h[16];
    const float* hin = hbuf + ((long)(b * NCHUNK + c) * D_INNER + d) * 16;
    #pragma unroll
    for (int s = 0; s < 16; s++) h[s] = hin[s];

    const float* dptr = delta + ((long)b * SEQ + t0) * D_INNER + d;
    const u16*   uptr = u     + ((long)b * SEQ + t0) * D_INNER + d;
    const float* zptr = z     + ((long)b * SEQ + t0) * D_INNER + d;
    const float* xp   = xdbc  + ((long)b * SEQ + t0) * XPROJ_N;
    u16* yptr = y + ((long)b * SEQ + t0) * D_INNER + d;

    for (int t = 0; t < CHUNK_T; t++) {
        float dl = dptr[(long)t * D_INNER];
        float uu = bf2f(uptr[(long)t * D_INNER]);
        float zl = zptr[(long)t * D_INNER];
        f32x4 B0 = *(const f32x4*)(xp + t * XPROJ_N + DT_RANK);
        f32x4 B1 = *(const f32x4*)(xp + t * XPROJ_N + DT_RANK + 4);
        f32x4 B2 = *(const f32x4*)(xp + t * XPROJ_N + DT_RANK + 8);
        f32x4 B3 = *(const f32x4*)(xp + t * XPROJ_N + DT_RANK + 12);
        f32x4 C0 = *(const f32x4*)(xp + t * XPROJ_N + DT_RANK + 16);
        f32x4 C1 = *(const f32x4*)(xp + t * XPROJ_N + DT_RANK + 20);
        f32x4 C2 = *(const f32x4*)(xp + t * XPROJ_N + DT_RANK + 24);
        f32x4 C3 = *(const f32x4*)(xp + t * XPROJ_N + DT_RANK + 28);
        float Bv[16] = {B0[0],B0[1],B0[2],B0[3], B1[0],B1[1],B1[2],B1[3],
                        B2[0],B2[1],B2[2],B2[3], B3[0],B3[1],B3[2],B3[3]};
        float Cv[16] = {C0[0],C0[1],C0[2],C0[3], C1[0],C1[1],C1[2],C1[3],
                        C2[0],C2[1],C2[2],C2[3], C3[0],C3[1],C3[2],C3[3]};
        float dlu = dl * uu;
        float p0 = 0.f, p1 = 0.f, p2 = 0.f, p3 = 0.f;
        #pragma unroll
        for (int s = 0; s < 16; s += 4) {
            h[s]   = h[s]   * exp2f(dl * Af[s])   + dlu * Bv[s];
            h[s+1] = h[s+1] * exp2f(dl * Af[s+1]) + dlu * Bv[s+1];
            h[s+2] = h[s+2] * exp2f(dl * Af[s+2]) + dlu * Bv[s+2];
            h[s+3] = h[s+3] * exp2f(dl * Af[s+3]) + dlu * Bv[s+3];
            p0 += h[s]   * Cv[s];
            p1 += h[s+1] * Cv[s+1];
            p2 += h[s+2] * Cv[s+2];
            p3 += h[s+3] * Cv[s+3];
        }
        float acc = (p0 + p1) + (p2 + p3);
        float sz = zl / (1.f + __expf(-zl));
        float yy = (acc + uu * Dd) * sz;
        yptr[(long)t * D_INNER] = f2bf(yy);
    }
}

// layernorm over sum of 2 split-K partials
__global__ __launch_bounds__(256)
void layernorm_kernel(const float* __restrict__ pa, const float* __restrict__ pb,
                      const float* __restrict__ gamma, const float* __restrict__ beta,
                      float* __restrict__ out)
{
    const long row = blockIdx.x;
    const long base = row * DIM;
    int tid = threadIdx.x;
    float v[4];
    float sum = 0.f, sq = 0.f;
    #pragma unroll
    for (int i = 0; i < 4; i++) {
        long c = base + tid + i * 256;
        v[i] = pa[c] + pb[c];
        sum += v[i];
        sq  += v[i] * v[i];
    }
    #pragma unroll
    for (int off = 1; off < 64; off <<= 1) {
        sum += __shfl_xor(sum, off);
        sq  += __shfl_xor(sq, off);
    }
    __shared__ float ssum[4], ssq[4];
    int w = tid >> 6;
    if ((tid & 63) == 0) { ssum[w] = sum; ssq[w] = sq; }
    __syncthreads();
    float ts = ssum[0] + ssum[1] + ssum[2] + ssum[3];
    float tq = ssq[0] + ssq[1] + ssq[2] + ssq[3];
    float mean = ts * (1.f / DIM);
    float var  = tq * (1.f / DIM) - mean * mean;
    float rstd = rsqrtf(var + 1e-5f);
    float* o = out + base;
    #pragma unroll
    for (int i = 0; i < 4; i++) {
        int c = tid + i * 256;
        o[c] = (v[i] - mean) * rstd * gamma[c] + beta[c];
    }
}

extern "C" void kernel_launch(void* const* d_in, const int* in_sizes, int n_in,
                              void* d_out, int out_size, void* d_ws, size_t ws_size,
                              hipStream_t stream)
{
    const float* x      = (const float*)d_in[0];
    const float* W_in   = (const float*)d_in[1];
    const float* conv_w = (const float*)d_in[2];
    const float* conv_b = (const float*)d_in[3];
    const float* W_xproj= (const float*)d_in[4];
    const float* W_dt   = (const float*)d_in[5];
    const float* b_dt   = (const float*)d_in[6];
    const float* A_log  = (const float*)d_in[7];
    const float* Dv     = (const float*)d_in[8];
    const float* W_out  = (const float*)d_in[9];
    const float* gamma  = (const float*)d_in[10];
    const float* beta   = (const float*)d_in[11];

    char* ws = (char*)d_ws;
    // [0, 16.78M): xc (steps 1-2) -> gemm3 partials + xdh/xdl -> hbuf/sdel
    u16*   xc    = (u16*)(ws);
    float* g3p   = (float*)(ws);                 // 8 x 1.57 MB = 12.58 MB
    u16*   xdh   = (u16*)(ws + 12582912);        // 1.57 MB
    u16*   xdl   = (u16*)(ws + 14155776);        // 1.57 MB
    float* hbuf  = (float*)(ws);                 // 8.39 MB (scan)
    float* sdel  = (float*)(ws + 8388608);       // 0.52 MB
    // [16.78M, 50.3M): z f32 -> opre partials (2 x 16.78 MB)
    float* z     = (float*)(ws + 16777216);
    float* opre  = (float*)(ws + 16777216);
    // [50.3M, 67.1M): u bf16 -> W_out splits (after scanC)
    u16*   u     = (u16*)(ws + 50331648);
    u16*   wouth = (u16*)(ws + 50331648);
    u16*   woutl = (u16*)(ws + 54525952);
    // [67.1M, 100.66M): x/W_in splits -> delta f32
    u16*   xh    = (u16*)(ws + 67108864);
    u16*   xl    = (u16*)(ws + 75497472);
    u16*   wh    = (u16*)(ws + 83886080);
    u16*   wl    = (u16*)(ws + 92274688);
    float* delta = (float*)(ws + 67108864);
    // [100.66M, 103.6M): xdbc f32 + persistent small splits
    float* xdbc  = (float*)(ws + 100663296);     // 1.57 MB
    u16*   wxh   = (u16*)(ws + 102236160);       // 0.39 MB
    u16*   wxl   = (u16*)(ws + 102629376);
    u16*   wdth  = (u16*)(ws + 103022592);       // 0.26 MB
    u16*   wdtl  = (u16*)(ws + 103284736);       // end 103.55 MB
    u16*   yb    = (u16*)d_out;

    // 0) all pre-splits except W_out in one launch
    megasplit4<<<34048, 256, 0, stream>>>(x, xh, xl, W_in, wh, wl,
                                          W_xproj, wxh, wxl, W_dt, wdth, wdtl);
    // 1) xz = x @ W_in^T -> xc bf16 | z f32   (M=4096,N=4096,K=1024)
    gemm128<3, EPI_XZ><<<dim3(32, 32), 256, 0, stream>>>(
        xh, xl, DIM, wh, wl, DIM, xc, z, 0, DIM, nullptr);
    // 2) u = silu(conv4(xc)+cb)
    conv_silu<<<4096, 256, 0, stream>>>(xc, conv_w, conv_b, u);
    // 3) gemm3 partials (split-K=8, no atomics) + combine(-> xdbc, xdh, xdl)
    gemm3_skp<<<dim3(3, 128, 8), 64, 0, stream>>>(
        u, D_INNER, wxh, wxl, D_INNER, g3p, XPROJ_N, 256);
    combine3<<<1536, 256, 0, stream>>>(g3p, xdbc, xdh, xdl);
    // 4) delta = softplus(dt @ W_dt^T + b_dt)  (M=4096,N=2048,K=64)
    gemm_dt32<<<dim3(64, 128), 64, 0, stream>>>(
        xdh, xdl, XPROJ_N, wdth, wdtl, DT_RANK, delta, D_INNER, b_dt);
    // 5) chunked parallel scan
    scan_partA<<<dim3(8, NCHUNK, BSZ), 256, 0, stream>>>(delta, u, xdbc, A_log, hbuf, sdel);
    scan_fixup<<<256, 256, 0, stream>>>(hbuf, sdel, A_log);
    scan_partC<<<dim3(8, NCHUNK, BSZ), 256, 0, stream>>>(delta, u, xdbc, z, A_log, Dv, hbuf, yb);
    // 5b) split W_out (into dead u region)
    split_kernel<<<8192, 256, 0, stream>>>(W_out, wouth, woutl, N_WO);
    // 6) opre[kz] = yb @ W_out^T slice  (split-K=2)
    gemm128_sk2<<<dim3(8, 32, 2), 256, 0, stream>>>(
        yb, D_INNER, wouth, woutl, D_INNER, opre, DIM, 1024);
    // 7) layernorm over sum of partials -> d_out f32
    layernorm_kernel<<<4096, 256, 0, stream>>>(
        opre, opre + 4194304, gamma, beta, (float*)d_out);
}